// Round 1
// baseline (175375.427 us; speedup 1.0000x reference)
//
#include <hip/hip_runtime.h>
#include <hip/hip_cooperative_groups.h>
#include <math.h>
#include <string.h>

namespace cg = cooperative_groups;

// ---------------- problem constants ----------------
#define TOUT 500
#define AOFF 1296000   // alignments offset in d_out
#define GOFF 1280000   // gate offset in d_out

// Threefry bits combine mode for 32-bit random bits (jax partitionable path):
//   0: bits = o0 ^ o1   (jax >= 0.4.36 default, partitionable)
//   1: bits = o0        (alternate guess if 0 fails)
// If both fail: implement pre-partitionable "halves" scheme (see notes in round log).
#define TF_BITS_XOR 1

struct Params {
  const float *memory, *dec_in, *pw1, *pw2, *awih, *awhh, *abih, *abhh;
  const float *qw, *mw, *vw, *lcw, *ldw, *dwih, *dwhh, *dbih, *dbhh;
  const float *pjw, *pjb, *gw, *gb;
  const int* mlen;
  float* out;
  // workspace
  float *ah0, *ah1, *dh0, *dh1, *ctx0, *ctx1, *aw, *awcum;
  float *pm, *loc2, *pre, *x1;
  float *w1t, *w2t, *qwt, *mwt;
  unsigned *mma, *mmd, *mm1, *mm2;
};

// ---------------- threefry2x32 (20 rounds), matches jax ----------------
__host__ __device__ inline void tf_block(unsigned k0, unsigned k1, unsigned x0, unsigned x1,
                                         unsigned& o0, unsigned& o1) {
  unsigned ks2 = k0 ^ k1 ^ 0x1BD11BDAu;
  x0 += k0; x1 += k1;
#define TFR(r) { x0 += x1; x1 = (x1 << r) | (x1 >> (32 - r)); x1 ^= x0; }
  TFR(13) TFR(15) TFR(26) TFR(6)
  x0 += k1;  x1 += ks2 + 1u;
  TFR(17) TFR(29) TFR(16) TFR(24)
  x0 += ks2; x1 += k0 + 2u;
  TFR(13) TFR(15) TFR(26) TFR(6)
  x0 += k0;  x1 += k1 + 3u;
  TFR(17) TFR(29) TFR(16) TFR(24)
  x0 += k1;  x1 += ks2 + 4u;
  TFR(13) TFR(15) TFR(26) TFR(6)
  x0 += ks2; x1 += k0 + 5u;
#undef TFR
  o0 = x0; o1 = x1;
}

__device__ inline float sigf(float x) { return 1.f / (1.f + __expf(-x)); }
__device__ inline float tanh_fast(float x) {
  float ax = fabsf(x);
  float t = __expf(-2.f * ax);
  float r = (1.f - t) / (1.f + t);
  return copysignf(r, x);
}

#define LD4(p) (*(const float4*)(p))

// ---------------- mask generation (bit-packed) ----------------
// ma: 500*32*1024 bits = 512000 words (key k3, p=0.9)
// md: 512000 words (k4, p=0.9)
// m1: 501*32*256 bits = 128256 words (k1, p=0.5)
// m2: 128256 words (k2, p=0.5)
__global__ void maskgen_kernel(Params p, unsigned k1a, unsigned k1b, unsigned k2a, unsigned k2b,
                               unsigned k3a, unsigned k3b, unsigned k4a, unsigned k4b) {
  int t = blockIdx.x * 256 + threadIdx.x;
  unsigned ka, kb; unsigned* dst; float pp;
  if (t < 512000)       { ka = k3a; kb = k3b; dst = p.mma; pp = 0.9f; }
  else if (t < 1024000) { t -= 512000;  ka = k4a; kb = k4b; dst = p.mmd; pp = 0.9f; }
  else if (t < 1152256) { t -= 1024000; ka = k1a; kb = k1b; dst = p.mm1; pp = 0.5f; }
  else if (t < 1280512) { t -= 1152256; ka = k2a; kb = k2b; dst = p.mm2; pp = 0.5f; }
  else return;
  unsigned word = 0u;
  for (int i = 0; i < 32; ++i) {
    unsigned o0, o1;
    tf_block(ka, kb, 0u, (unsigned)t * 32u + (unsigned)i, o0, o1);
#if TF_BITS_XOR
    unsigned bits = o0 ^ o1;
#else
    unsigned bits = o0;
#endif
    unsigned fb = (bits >> 9) | 0x3f800000u;
    float u = __uint_as_float(fb) - 1.0f;
    if (u < pp) word |= (1u << i);
  }
  dst[t] = word;
}

// ---------------- weight transposes for coalescing ----------------
__global__ void prep_transpose(Params p) {
  int i = blockIdx.x * 256 + threadIdx.x;
  if (i < 20480) {                       // w1t[k*256+u] = pw1[u*80+k]
    int k = i >> 8, u = i & 255;
    p.w1t[i] = p.pw1[u * 80 + k];
  } else if (i < 20480 + 65536) {        // w2t[k*256+u] = pw2[u*256+k]
    int j = i - 20480; int k = j >> 8, u = j & 255;
    p.w2t[j] = p.pw2[u * 256 + k];
  } else if (i < 20480 + 65536 + 131072) { // qwt[k*128+a] = qw[a*1024+k]
    int j = i - 20480 - 65536; int k = j >> 7, a = j & 127;
    p.qwt[j] = p.qw[a * 1024 + k];
  } else if (i < 20480 + 65536 + 131072 + 65536) { // mwt[k*128+a] = mw[a*512+k]
    int j = i - 20480 - 65536 - 131072; int k = j >> 7, a = j & 127;
    p.mwt[j] = p.mw[a * 512 + k];
  }
}

// ---------------- prenet layer 1: X1 = relu(dec_in @ W1^T) * m1 ----------------
__global__ void prenet1_kernel(Params p) {
  __shared__ float din[8][80];
  int wg = blockIdx.x, tid = threadIdx.x;
  int r0 = wg * 8;
  for (int idx = tid; idx < 8 * 80; idx += 256) {
    int j = idx / 80, kk = idx % 80;
    int r = r0 + j; int t = r >> 5, b = r & 31;
    din[j][kk] = (t == 0) ? 0.f : p.dec_in[(size_t)b * 40000 + (size_t)kk * 500 + (t - 1)];
  }
  __syncthreads();
  float acc[8] = {0,0,0,0,0,0,0,0};
  for (int k = 0; k < 80; ++k) {
    float wv = p.w1t[k * 256 + tid];
#pragma unroll
    for (int j = 0; j < 8; ++j) acc[j] += din[j][k] * wv;
  }
  for (int j = 0; j < 8; ++j) {
    int r = r0 + j;
    unsigned e = (unsigned)r * 256u + tid;
    float mv = ((p.mm1[e >> 5] >> (e & 31)) & 1u) ? 2.0f : 0.0f;
    p.x1[(size_t)r * 256 + tid] = fmaxf(acc[j], 0.f) * mv;
  }
}

// ---------------- prenet layer 2 ----------------
__global__ void prenet2_kernel(Params p) {
  __shared__ float rows[8][256];
  int wg = blockIdx.x, tid = threadIdx.x;
  int r0 = wg * 8;
  for (int idx = tid; idx < 8 * 256; idx += 256) {
    int j = idx >> 8, kk = idx & 255;
    rows[j][kk] = p.x1[(size_t)(r0 + j) * 256 + kk];
  }
  __syncthreads();
  float acc[8] = {0,0,0,0,0,0,0,0};
  for (int k = 0; k < 256; ++k) {
    float wv = p.w2t[k * 256 + tid];
#pragma unroll
    for (int j = 0; j < 8; ++j) acc[j] += rows[j][k] * wv;
  }
  for (int j = 0; j < 8; ++j) {
    int r = r0 + j;
    unsigned e = (unsigned)r * 256u + tid;
    float mv = ((p.mm2[e >> 5] >> (e & 31)) & 1u) ? 2.0f : 0.0f;
    p.pre[(size_t)r * 256 + tid] = fmaxf(acc[j], 0.f) * mv;
  }
}

// ---------------- processed_memory: pm[b][t][a] = sum_e mem[b][t][e]*mw[a][e] ----------------
__global__ void pm_kernel(Params p) {
  __shared__ float mrows[16][512];
  int wg = blockIdx.x;           // 512 = 32 b * 16 tchunks
  int b = wg >> 4, tc = wg & 15;
  int tid = threadIdx.x;         // 128
  int t0 = tc * 16;
  for (int idx = tid; idx < 16 * 512; idx += 128) {
    int i = idx >> 9, k = idx & 511;
    mrows[i][k] = p.memory[((size_t)b * 256 + t0 + i) * 512 + k];
  }
  __syncthreads();
  float acc[16];
#pragma unroll
  for (int i = 0; i < 16; ++i) acc[i] = 0.f;
  for (int k = 0; k < 512; ++k) {
    float wv = p.mwt[k * 128 + tid];
#pragma unroll
    for (int i = 0; i < 16; ++i) acc[i] += mrows[i][k] * wv;
  }
  for (int i = 0; i < 16; ++i)
    p.pm[((size_t)b * 256 + t0 + i) * 128 + tid] = acc[i];
}

// ---------------- persistent cooperative scan kernel ----------------
// grid = 256 WGs x 512 threads. Per s in [0,500]:
//   X: attLSTM_s (tid<256) || decLSTM_{s-1} (tid>=256) || conv+dense_s (all)
//   grid.sync()
//   B: full attention_s (wg<32, one b per WG) || mel/gate_{s-1} (wg>=32)
//   grid.sync()
__global__ void __launch_bounds__(512) scan_kernel(Params p) {
  cg::grid_group grid = cg::this_grid();
  const int wg = blockIdx.x;
  const int tid = threadIdx.x;

  __shared__ float attc[4][32];   // att cell state (4 units of this WG x 32 batch)
  __shared__ float decc[4][32];
  __shared__ float gl[2][16][32]; // gate exchange [att/dec][col][b]
  __shared__ float sm[1536];      // scratch union

  if (tid < 128) { attc[tid >> 5][tid & 31] = 0.f; decc[tid >> 5][tid & 31] = 0.f; }

  for (int s = 0; s <= 500; ++s) {
    const int sb = s & 1;
    const float* ah_prev  = sb ? p.ah0 : p.ah1;  // ah_{s-1}
    float*       ah_cur   = sb ? p.ah1 : p.ah0;  // ah_s
    const float* dh_prev2 = sb ? p.dh1 : p.dh0;  // dh_{s-2}
    float*       dh_out   = sb ? p.dh0 : p.dh1;  // dh_{s-1}
    const float* ctx_prev = sb ? p.ctx0 : p.ctx1; // ctx_{s-1}
    float*       ctx_cur  = sb ? p.ctx1 : p.ctx0; // ctx_s

    // ================= Phase X =================
    if (tid < 256) {
      if (s < 500) {
        const int c = tid & 15, bt = tid >> 4;
        const int q = c >> 2, ul = c & 3;
        const int col = q * 1024 + wg * 4 + ul;
        const int b0 = bt, b1 = bt + 16;
        const float* wih = p.awih + (size_t)col * 768;
        const float* whh = p.awhh + (size_t)col * 1024;
        float4 A0 = {0,0,0,0}, A1 = {0,0,0,0};
        const float* pn0 = p.pre + ((size_t)s * 32 + b0) * 256;
        const float* pn1 = p.pre + ((size_t)s * 32 + b1) * 256;
#pragma unroll 4
        for (int k = 0; k < 256; k += 4) {
          float4 wv = LD4(wih + k);
          float4 x0 = LD4(pn0 + k), x1 = LD4(pn1 + k);
          A0.x += x0.x*wv.x; A0.y += x0.y*wv.y; A0.z += x0.z*wv.z; A0.w += x0.w*wv.w;
          A1.x += x1.x*wv.x; A1.y += x1.y*wv.y; A1.z += x1.z*wv.z; A1.w += x1.w*wv.w;
        }
        const float* cx0 = ctx_prev + b0 * 512;
        const float* cx1 = ctx_prev + b1 * 512;
#pragma unroll 4
        for (int k = 0; k < 512; k += 4) {
          float4 wv = LD4(wih + 256 + k);
          float4 x0 = LD4(cx0 + k), x1 = LD4(cx1 + k);
          A0.x += x0.x*wv.x; A0.y += x0.y*wv.y; A0.z += x0.z*wv.z; A0.w += x0.w*wv.w;
          A1.x += x1.x*wv.x; A1.y += x1.y*wv.y; A1.z += x1.z*wv.z; A1.w += x1.w*wv.w;
        }
        const float* xh0 = ah_prev + b0 * 1024;
        const float* xh1 = ah_prev + b1 * 1024;
#pragma unroll 4
        for (int k = 0; k < 1024; k += 4) {
          float4 wv = LD4(whh + k);
          float4 x0 = LD4(xh0 + k), x1 = LD4(xh1 + k);
          A0.x += x0.x*wv.x; A0.y += x0.y*wv.y; A0.z += x0.z*wv.z; A0.w += x0.w*wv.w;
          A1.x += x1.x*wv.x; A1.y += x1.y*wv.y; A1.z += x1.z*wv.z; A1.w += x1.w*wv.w;
        }
        float bias = p.abih[col] + p.abhh[col];
        gl[0][c][b0] = A0.x + A0.y + A0.z + A0.w + bias;
        gl[0][c][b1] = A1.x + A1.y + A1.z + A1.w + bias;
      }
    } else {
      if (s >= 1) {
        const int t2 = tid - 256;
        const int c = t2 & 15, bt = t2 >> 4;
        const int q = c >> 2, ul = c & 3;
        const int col = q * 1024 + wg * 4 + ul;
        const int b0 = bt, b1 = bt + 16;
        const float* wih = p.dwih + (size_t)col * 1536;
        const float* whh = p.dwhh + (size_t)col * 1024;
        float4 A0 = {0,0,0,0}, A1 = {0,0,0,0};
        const float* xa0 = ah_prev + b0 * 1024;
        const float* xa1 = ah_prev + b1 * 1024;
#pragma unroll 4
        for (int k = 0; k < 1024; k += 4) {
          float4 wv = LD4(wih + k);
          float4 x0 = LD4(xa0 + k), x1 = LD4(xa1 + k);
          A0.x += x0.x*wv.x; A0.y += x0.y*wv.y; A0.z += x0.z*wv.z; A0.w += x0.w*wv.w;
          A1.x += x1.x*wv.x; A1.y += x1.y*wv.y; A1.z += x1.z*wv.z; A1.w += x1.w*wv.w;
        }
        const float* xc0 = ctx_prev + b0 * 512;
        const float* xc1 = ctx_prev + b1 * 512;
#pragma unroll 4
        for (int k = 0; k < 512; k += 4) {
          float4 wv = LD4(wih + 1024 + k);
          float4 x0 = LD4(xc0 + k), x1 = LD4(xc1 + k);
          A0.x += x0.x*wv.x; A0.y += x0.y*wv.y; A0.z += x0.z*wv.z; A0.w += x0.w*wv.w;
          A1.x += x1.x*wv.x; A1.y += x1.y*wv.y; A1.z += x1.z*wv.z; A1.w += x1.w*wv.w;
        }
        const float* xh0 = dh_prev2 + b0 * 1024;
        const float* xh1 = dh_prev2 + b1 * 1024;
#pragma unroll 4
        for (int k = 0; k < 1024; k += 4) {
          float4 wv = LD4(whh + k);
          float4 x0 = LD4(xh0 + k), x1 = LD4(xh1 + k);
          A0.x += x0.x*wv.x; A0.y += x0.y*wv.y; A0.z += x0.z*wv.z; A0.w += x0.w*wv.w;
          A1.x += x1.x*wv.x; A1.y += x1.y*wv.y; A1.z += x1.z*wv.z; A1.w += x1.w*wv.w;
        }
        float bias = p.dbih[col] + p.dbhh[col];
        gl[1][c][b0] = A0.x + A0.y + A0.z + A0.w + bias;
        gl[1][c][b1] = A1.x + A1.y + A1.z + A1.w + bias;
      }
    }
    __syncthreads();
    // cell updates
    if (tid < 128) {
      if (s < 500) {
        int b = tid & 31, ul = tid >> 5;
        float gi = gl[0][ul][b], gf = gl[0][4 + ul][b], gg = gl[0][8 + ul][b], go = gl[0][12 + ul][b];
        float I = sigf(gi), F = sigf(gf), G = tanh_fast(gg), O = sigf(go);
        float c2 = F * attc[ul][b] + I * G;
        float h = O * tanh_fast(c2);
        attc[ul][b] = c2;
        int u = wg * 4 + ul;
        unsigned e = ((unsigned)s * 32 + b) * 1024u + u;
        float mv = ((p.mma[e >> 5] >> (e & 31)) & 1u) ? (1.f / 0.9f) : 0.f;
        ah_cur[b * 1024 + u] = h * mv;
      }
    } else if (tid >= 256 && tid < 384) {
      if (s >= 1) {
        int lt = tid - 256; int b = lt & 31, ul = lt >> 5;
        float gi = gl[1][ul][b], gf = gl[1][4 + ul][b], gg = gl[1][8 + ul][b], go = gl[1][12 + ul][b];
        float I = sigf(gi), F = sigf(gf), G = tanh_fast(gg), O = sigf(go);
        float c2 = F * decc[ul][b] + I * G;
        float h = O * tanh_fast(c2);
        decc[ul][b] = c2;
        int u = wg * 4 + ul;
        unsigned e = ((unsigned)(s - 1) * 32 + b) * 1024u + u;
        float mv = ((p.mmd[e >> 5] >> (e & 31)) & 1u) ? (1.f / 0.9f) : 0.f;
        dh_out[b * 1024 + u] = h * mv;
      }
    }
    __syncthreads();
    // location conv + dense for step s (uses aw_{s-1}, awcum_{s-1})
    if (s < 500) {
      int bb = wg >> 3, tcc = wg & 7;
      for (int oo = tid; oo < 1024; oo += 512) {
        int f = oo >> 5, tt = oo & 31;
        int t = tcc * 32 + tt;
        const float* wf = p.lcw + f * 62;
        float acc = 0.f;
        for (int k = 0; k < 31; ++k) {
          int ts = t + k - 15;
          if (ts >= 0 && ts < 256)
            acc += p.aw[bb * 256 + ts] * wf[k] + p.awcum[bb * 256 + ts] * wf[31 + k];
        }
        sm[f * 33 + tt] = acc;
      }
      __syncthreads();
      for (int oo = tid; oo < 4096; oo += 512) {
        int tt = oo >> 7, a = oo & 127;
        int t = tcc * 32 + tt;
        const float* lw = p.ldw + a * 32;
        float acc = 0.f;
#pragma unroll
        for (int f = 0; f < 32; ++f) acc += sm[f * 33 + tt] * lw[f];
        p.loc2[((size_t)bb * 256 + t) * 128 + a] = acc;
      }
    }

    grid.sync();

    // ================= Phase B =================
    if (wg < 32) {
      if (s < 500) {
        const int b = wg;
        // pq = ah_s[b] @ qw^T  (redundant-free: once per b)
        {
          int a = tid & 127, kg = tid >> 7;
          const float* ahb = ah_cur + b * 1024 + kg * 256;
          const float* qt = p.qwt + (size_t)(kg * 256) * 128 + a;
          float acc = 0.f;
          for (int j = 0; j < 256; ++j) acc += ahb[j] * qt[j * 128];
          sm[256 + kg * 128 + a] = acc;
          if (tid < 128) sm[128 + tid] = p.vw[tid];
        }
        __syncthreads();
        if (tid < 128) sm[tid] = sm[256 + tid] + sm[384 + tid] + sm[512 + tid] + sm[640 + tid];
        __syncthreads();
        // energies: e[t] = sum_a tanh(pq[a]+loc2+pm)*v[a]
        {
          int t = tid & 255, h2 = tid >> 8;
          const float* l2p = p.loc2 + ((size_t)b * 256 + t) * 128 + h2 * 64;
          const float* pmp = p.pm + ((size_t)b * 256 + t) * 128 + h2 * 64;
          float e = 0.f;
          for (int kk = 0; kk < 64; kk += 4) {
            float4 lv = LD4(l2p + kk), pv = LD4(pmp + kk);
            int a0 = h2 * 64 + kk;
            e += tanh_fast(sm[a0 + 0] + lv.x + pv.x) * sm[128 + a0 + 0];
            e += tanh_fast(sm[a0 + 1] + lv.y + pv.y) * sm[128 + a0 + 1];
            e += tanh_fast(sm[a0 + 2] + lv.z + pv.z) * sm[128 + a0 + 2];
            e += tanh_fast(sm[a0 + 3] + lv.w + pv.w) * sm[128 + a0 + 3];
          }
          sm[256 + h2 * 256 + t] = e;
        }
        __syncthreads();
        if (tid < 256) {
          float en = sm[256 + tid] + sm[512 + tid];
          float w = (tid < p.mlen[b]) ? __expf(en) : 0.f;  // no max-sub: |en| <= ~2.1
          sm[768 + tid] = w;
        }
        __syncthreads();
        if (tid < 32) {
          float sub = 0.f;
          for (int i = 0; i < 8; ++i) sub += sm[768 + tid * 8 + i];
          sm[256 + tid] = sub;
        }
        __syncthreads();
        if (tid == 0) {
          float S = 0.f;
          for (int i = 0; i < 32; ++i) S += sm[256 + i];
          sm[1281] = 1.f / S;
        }
        __syncthreads();
        if (tid < 256) {
          float awv = sm[768 + tid] * sm[1281];
          p.aw[b * 256 + tid] = awv;
          p.awcum[b * 256 + tid] += awv;
          p.out[(size_t)AOFF + (size_t)b * 128000 + (size_t)s * 256 + tid] = awv;
          sm[1024 + tid] = awv;
        }
        __syncthreads();
        // ctx_s[b] = aw_s @ memory[b]
        {
          const float* mb = p.memory + (size_t)b * 131072 + tid;
          float acc = 0.f;
#pragma unroll 4
          for (int t2 = 0; t2 < 256; ++t2) acc += sm[1024 + t2] * mb[(size_t)t2 * 512];
          ctx_cur[b * 512 + tid] = acc;
        }
      }
    } else {
      if (s >= 1) {
        // mel_{s-1}, gate_{s-1} from dhac = [dh_{s-1}, ctx_{s-1}]
        int idx = wg - 32;
        int b = idx / 7, c7 = idx % 7;
        int m0 = c7 * 12, mc = (c7 == 6) ? 8 : 12;
        const float* dhb = dh_out + b * 1024;
        const float* cxb = ctx_prev + b * 512;
        int mi = tid >> 5, kg = tid & 31;
        if (mi < mc) {
          int m = m0 + mi;
          const float* pw = p.pjw + (size_t)m * 1536 + kg * 48;
          float acc = 0.f;
          for (int j = 0; j < 48; ++j) {
            int k = kg * 48 + j;
            float x = (k < 1024) ? dhb[k] : cxb[k - 1024];
            acc += x * pw[j];
          }
          sm[mi * 32 + kg] = acc;
        }
        if (c7 == 6 && tid >= 384) {
          int kg2 = tid - 384;
          const float* gwp = p.gw + kg2 * 12;
          float acc = 0.f;
          for (int j = 0; j < 12; ++j) {
            int k = kg2 * 12 + j;
            float x = (k < 1024) ? dhb[k] : cxb[k - 1024];
            acc += x * gwp[j];
          }
          sm[512 + kg2] = acc;
        }
        __syncthreads();
        if (tid < mc) {
          float r = p.pjb[m0 + tid];
          for (int j = 0; j < 32; ++j) r += sm[tid * 32 + j];
          p.out[(size_t)b * 40000 + (size_t)(m0 + tid) * 500 + (s - 1)] = r;
        }
        if (c7 == 6 && tid == 384) {
          float r = p.gb[0];
          for (int j = 0; j < 128; ++j) r += sm[512 + j];
          p.out[(size_t)GOFF + (size_t)b * 500 + (s - 1)] = r;
        }
      }
    }

    grid.sync();
  }
}

// ---------------- host ----------------
extern "C" void kernel_launch(void* const* d_in, const int* in_sizes, int n_in,
                              void* d_out, int out_size, void* d_ws, size_t ws_size,
                              hipStream_t stream) {
  Params p;
  p.memory = (const float*)d_in[0];
  p.dec_in = (const float*)d_in[1];
  p.mlen   = (const int*)d_in[2];
  p.pw1  = (const float*)d_in[3];
  p.pw2  = (const float*)d_in[4];
  p.awih = (const float*)d_in[5];
  p.awhh = (const float*)d_in[6];
  p.abih = (const float*)d_in[7];
  p.abhh = (const float*)d_in[8];
  p.qw   = (const float*)d_in[9];
  p.mw   = (const float*)d_in[10];
  p.vw   = (const float*)d_in[11];
  p.lcw  = (const float*)d_in[12];
  p.ldw  = (const float*)d_in[13];
  p.dwih = (const float*)d_in[14];
  p.dwhh = (const float*)d_in[15];
  p.dbih = (const float*)d_in[16];
  p.dbhh = (const float*)d_in[17];
  p.pjw  = (const float*)d_in[18];
  p.pjb  = (const float*)d_in[19];
  p.gw   = (const float*)d_in[20];
  p.gb   = (const float*)d_in[21];
  p.out  = (float*)d_out;

  char* cur = (char*)d_ws;
  auto allocf = [&](size_t n) { float* r = (float*)cur; cur += n * sizeof(float); return r; };
  p.ah0 = allocf(32 * 1024); p.ah1 = allocf(32 * 1024);
  p.dh0 = allocf(32 * 1024); p.dh1 = allocf(32 * 1024);
  p.ctx0 = allocf(32 * 512); p.ctx1 = allocf(32 * 512);
  p.aw = allocf(32 * 256); p.awcum = allocf(32 * 256);
  size_t state_bytes = (size_t)(cur - (char*)d_ws);
  p.pm   = allocf((size_t)32 * 256 * 128);
  p.loc2 = allocf((size_t)32 * 256 * 128);
  p.pre  = allocf((size_t)500 * 32 * 256);
  p.x1   = allocf((size_t)500 * 32 * 256);
  p.w1t  = allocf(80 * 256);
  p.w2t  = allocf(256 * 256);
  p.qwt  = allocf(1024 * 128);
  p.mwt  = allocf(512 * 128);
  p.mma = (unsigned*)cur; cur += 512000u * 4;
  p.mmd = (unsigned*)cur; cur += 512000u * 4;
  p.mm1 = (unsigned*)cur; cur += 128256u * 4;
  p.mm2 = (unsigned*)cur; cur += 128256u * 4;

  (void)hipMemsetAsync(d_ws, 0, state_bytes, stream);

  // derive k1..k4 = split(key(1), 4) on host (partitionable/foldlike: key_i = block(key, 0, i))
  unsigned k[8];
  {
    unsigned o0, o1;
    tf_block(0u, 1u, 0u, 0u, o0, o1); k[0] = o0; k[1] = o1;  // k1 (m1)
    tf_block(0u, 1u, 0u, 1u, o0, o1); k[2] = o0; k[3] = o1;  // k2 (m2)
    tf_block(0u, 1u, 0u, 2u, o0, o1); k[4] = o0; k[5] = o1;  // k3 (att_drop)
    tf_block(0u, 1u, 0u, 3u, o0, o1); k[6] = o0; k[7] = o1;  // k4 (dec_drop)
  }

  maskgen_kernel<<<(1280512 + 255) / 256, 256, 0, stream>>>(p, k[0], k[1], k[2], k[3], k[4], k[5], k[6], k[7]);
  prep_transpose<<<(282624 + 255) / 256, 256, 0, stream>>>(p);
  prenet1_kernel<<<2000, 256, 0, stream>>>(p);
  prenet2_kernel<<<2000, 256, 0, stream>>>(p);
  pm_kernel<<<512, 128, 0, stream>>>(p);

  void* args[] = { (void*)&p };
  (void)hipLaunchCooperativeKernel((const void*)scan_kernel, dim3(256), dim3(512), args, 0, stream);
}

// Round 2
// 95041.211 us; speedup vs baseline: 1.8453x; 1.8453x over previous
//
#include <hip/hip_runtime.h>
#include <hip/hip_cooperative_groups.h>
#include <math.h>
#include <string.h>

namespace cg = cooperative_groups;

#define TOUT 500
#define AOFF 1296000
#define GOFF 1280000
#define TF_BITS_XOR 1

typedef float f32x4 __attribute__((ext_vector_type(4)));
typedef short bf16x8 __attribute__((ext_vector_type(8)));

struct Params {
  const float *memory, *dec_in, *pw1, *pw2, *awih, *awhh, *abih, *abhh;
  const float *qw, *mw, *vw, *lcw, *ldw, *dwih, *dwhh, *dbih, *dbhh;
  const float *pjw, *pjb, *gw, *gb;
  const int* mlen;
  float* out;
  // fp32 state
  float *ah0, *ah1, *dh0, *dh1, *ctx0, *ctx1, *aw, *awcum;
  // bf16 state mirrors
  unsigned short *ahb0, *ahb1, *dhb0, *dhb1, *ctxb0, *ctxb1;
  // static fp32
  float *x1, *w1t, *w2t, *mwt, *ldwt, *ba, *bd;
  // static bf16
  unsigned short *pre_bf, *pm_bf, *loc2_bf, *mem_bf, *qw_bf, *wpa, *wpd;
  unsigned *mma, *mmd, *mm1, *mm2;
};

// ---------------- threefry2x32 (matches jax partitionable path) ----------------
__host__ __device__ inline void tf_block(unsigned k0, unsigned k1, unsigned x0, unsigned x1,
                                         unsigned& o0, unsigned& o1) {
  unsigned ks2 = k0 ^ k1 ^ 0x1BD11BDAu;
  x0 += k0; x1 += k1;
#define TFR(r) { x0 += x1; x1 = (x1 << r) | (x1 >> (32 - r)); x1 ^= x0; }
  TFR(13) TFR(15) TFR(26) TFR(6)
  x0 += k1;  x1 += ks2 + 1u;
  TFR(17) TFR(29) TFR(16) TFR(24)
  x0 += ks2; x1 += k0 + 2u;
  TFR(13) TFR(15) TFR(26) TFR(6)
  x0 += k0;  x1 += k1 + 3u;
  TFR(17) TFR(29) TFR(16) TFR(24)
  x0 += k1;  x1 += ks2 + 4u;
  TFR(13) TFR(15) TFR(26) TFR(6)
  x0 += ks2; x1 += k0 + 5u;
#undef TFR
  o0 = x0; o1 = x1;
}

__device__ inline float sigf(float x) { return 1.f / (1.f + __expf(-x)); }
__device__ inline float tanh_fast(float x) {
  float ax = fabsf(x);
  float t = __expf(-2.f * ax);
  float r = (1.f - t) / (1.f + t);
  return copysignf(r, x);
}
__device__ inline unsigned short f2bf(float f) {
  unsigned u = __float_as_uint(f);
  unsigned r = (u + 0x7FFFu + ((u >> 16) & 1u)) >> 16;
  return (unsigned short)r;
}
__device__ inline float bf2f(unsigned short u) {
  return __uint_as_float((unsigned)u << 16);
}

#define LD4(p) (*(const float4*)(p))

// ---------------- mask generation (bit-packed) ----------------
__global__ void maskgen_kernel(Params p, unsigned k1a, unsigned k1b, unsigned k2a, unsigned k2b,
                               unsigned k3a, unsigned k3b, unsigned k4a, unsigned k4b) {
  int t = blockIdx.x * 256 + threadIdx.x;
  unsigned ka, kb; unsigned* dst; float pp;
  if (t < 512000)       { ka = k3a; kb = k3b; dst = p.mma; pp = 0.9f; }
  else if (t < 1024000) { t -= 512000;  ka = k4a; kb = k4b; dst = p.mmd; pp = 0.9f; }
  else if (t < 1152256) { t -= 1024000; ka = k1a; kb = k1b; dst = p.mm1; pp = 0.5f; }
  else if (t < 1280512) { t -= 1152256; ka = k2a; kb = k2b; dst = p.mm2; pp = 0.5f; }
  else return;
  unsigned word = 0u;
  for (int i = 0; i < 32; ++i) {
    unsigned o0, o1;
    tf_block(ka, kb, 0u, (unsigned)t * 32u + (unsigned)i, o0, o1);
#if TF_BITS_XOR
    unsigned bits = o0 ^ o1;
#else
    unsigned bits = o0;
#endif
    unsigned fb = (bits >> 9) | 0x3f800000u;
    float u = __uint_as_float(fb) - 1.0f;
    if (u < pp) word |= (1u << i);
  }
  dst[t] = word;
}

// ---------------- misc static prep (transposes, bf16 converts, biases) ----------------
__global__ void prep_misc(Params p) {
  int i = blockIdx.x * 256 + threadIdx.x;
  if (i < 20480) { // w1t[k*256+u] = pw1[u*80+k]
    int k = i >> 8, u = i & 255;
    p.w1t[i] = p.pw1[u * 80 + k];
    return;
  }
  i -= 20480;
  if (i < 65536) { // w2t[k*256+u]
    int k = i >> 8, u = i & 255;
    p.w2t[i] = p.pw2[u * 256 + k];
    return;
  }
  i -= 65536;
  if (i < 65536) { // mwt[k*128+a] = mw[a*512+k]
    int k = i >> 7, a = i & 127;
    p.mwt[i] = p.mw[a * 512 + k];
    return;
  }
  i -= 65536;
  if (i < 131072) { // qw_bf flat convert [a][k]
    p.qw_bf[i] = f2bf(p.qw[i]);
    return;
  }
  i -= 131072;
  if (i < 4096) { // ldwt[f*128+a] = ldw[a*32+f]
    int f = i >> 7, a = i & 127;
    p.ldwt[i] = p.ldw[a * 32 + f];
    return;
  }
  i -= 4096;
  if (i < 4096) { // bias att permuted
    int col = (i & 3) * 1024 + (i >> 2);
    p.ba[i] = p.abih[col] + p.abhh[col];
    return;
  }
  i -= 4096;
  if (i < 4096) {
    int col = (i & 3) * 1024 + (i >> 2);
    p.bd[i] = p.dbih[col] + p.dbhh[col];
    return;
  }
  i -= 4096;
  if (i < 4194304) { // mem_bf flat convert
    p.mem_bf[i] = f2bf(p.memory[i]);
    return;
  }
}

// ---------------- weight packing into MFMA B-fragment order ----------------
// wpa[T][c][lane][8]: B[k=32c+8*(lane>>4)+j][n=T*16+(lane&15)], col = (n&3)*1024 + (n>>2)
__global__ void pack_att(Params p) {
  int idx = blockIdx.x * 256 + threadIdx.x;
  if (idx >= 256 * 56 * 64) return;
  int l = idx & 63;
  int c = (idx >> 6) % 56;
  int T = idx / (56 * 64);
  int n = T * 16 + (l & 15);
  int col = (n & 3) * 1024 + (n >> 2);
  int kb = c * 32 + 8 * (l >> 4);
  bf16x8 v;
#pragma unroll
  for (int j = 0; j < 8; ++j) {
    int k = kb + j;
    float f = (k < 768) ? p.awih[(size_t)col * 768 + k] : p.awhh[(size_t)col * 1024 + k - 768];
    v[j] = (short)f2bf(f);
  }
  *(bf16x8*)(p.wpa + (size_t)idx * 8) = v;
}
__global__ void pack_dec(Params p) {
  int idx = blockIdx.x * 256 + threadIdx.x;
  if (idx >= 256 * 80 * 64) return;
  int l = idx & 63;
  int c = (idx >> 6) % 80;
  int T = idx / (80 * 64);
  int n = T * 16 + (l & 15);
  int col = (n & 3) * 1024 + (n >> 2);
  int kb = c * 32 + 8 * (l >> 4);
  bf16x8 v;
#pragma unroll
  for (int j = 0; j < 8; ++j) {
    int k = kb + j;
    float f = (k < 1536) ? p.dwih[(size_t)col * 1536 + k] : p.dwhh[(size_t)col * 1024 + k - 1536];
    v[j] = (short)f2bf(f);
  }
  *(bf16x8*)(p.wpd + (size_t)idx * 8) = v;
}

// ---------------- prenet ----------------
__global__ void prenet1_kernel(Params p) {
  __shared__ float din[8][80];
  int wg = blockIdx.x, tid = threadIdx.x;
  int r0 = wg * 8;
  for (int idx = tid; idx < 8 * 80; idx += 256) {
    int j = idx / 80, kk = idx % 80;
    int r = r0 + j; int t = r >> 5, b = r & 31;
    din[j][kk] = (t == 0) ? 0.f : p.dec_in[(size_t)b * 40000 + (size_t)kk * 500 + (t - 1)];
  }
  __syncthreads();
  float acc[8] = {0,0,0,0,0,0,0,0};
  for (int k = 0; k < 80; ++k) {
    float wv = p.w1t[k * 256 + tid];
#pragma unroll
    for (int j = 0; j < 8; ++j) acc[j] += din[j][k] * wv;
  }
  for (int j = 0; j < 8; ++j) {
    int r = r0 + j;
    unsigned e = (unsigned)r * 256u + tid;
    float mv = ((p.mm1[e >> 5] >> (e & 31)) & 1u) ? 2.0f : 0.0f;
    p.x1[(size_t)r * 256 + tid] = fmaxf(acc[j], 0.f) * mv;
  }
}
__global__ void prenet2_kernel(Params p) {
  __shared__ float rows[8][256];
  int wg = blockIdx.x, tid = threadIdx.x;
  int r0 = wg * 8;
  for (int idx = tid; idx < 8 * 256; idx += 256) {
    int j = idx >> 8, kk = idx & 255;
    rows[j][kk] = p.x1[(size_t)(r0 + j) * 256 + kk];
  }
  __syncthreads();
  float acc[8] = {0,0,0,0,0,0,0,0};
  for (int k = 0; k < 256; ++k) {
    float wv = p.w2t[k * 256 + tid];
#pragma unroll
    for (int j = 0; j < 8; ++j) acc[j] += rows[j][k] * wv;
  }
  for (int j = 0; j < 8; ++j) {
    int r = r0 + j;
    unsigned e = (unsigned)r * 256u + tid;
    float mv = ((p.mm2[e >> 5] >> (e & 31)) & 1u) ? 2.0f : 0.0f;
    p.pre_bf[(size_t)r * 256 + tid] = f2bf(fmaxf(acc[j], 0.f) * mv);
  }
}

// ---------------- processed_memory -> bf16 ----------------
__global__ void pm_kernel(Params p) {
  __shared__ float mrows[16][512];
  int wg = blockIdx.x;
  int b = wg >> 4, tc = wg & 15;
  int tid = threadIdx.x;
  int t0 = tc * 16;
  for (int idx = tid; idx < 16 * 512; idx += 128) {
    int i = idx >> 9, k = idx & 511;
    mrows[i][k] = p.memory[((size_t)b * 256 + t0 + i) * 512 + k];
  }
  __syncthreads();
  float acc[16];
#pragma unroll
  for (int i = 0; i < 16; ++i) acc[i] = 0.f;
  for (int k = 0; k < 512; ++k) {
    float wv = p.mwt[k * 128 + tid];
#pragma unroll
    for (int i = 0; i < 16; ++i) acc[i] += mrows[i][k] * wv;
  }
  for (int i = 0; i < 16; ++i)
    p.pm_bf[((size_t)b * 256 + t0 + i) * 128 + tid] = f2bf(acc[i]);
}

// ---------------- persistent cooperative scan kernel ----------------
// 256 WGs x 512. WGs 0..127: att-LSTM (8 units each) + conv. WGs 128..255: dec-LSTM.
// Phase B: WGs 0..31 attention (1 batch each), 32..255 mel/gate projection.
__global__ void __launch_bounds__(512) scan_kernel(Params p) {
  cg::grid_group grid = cg::this_grid();
  const int wg = blockIdx.x;
  const int tid = threadIdx.x;
  const int lane = tid & 63;
  const int v = tid >> 6;

  __shared__ float pl[8192];       // 8 waves x 1024 partials
  __shared__ float gates[32 * 33];
  __shared__ float cst[256];       // persistent cell state (8 units x 32 b)
  __shared__ float locT[32 * 65];
  __shared__ float sm[1536];

  if (tid < 256) cst[tid] = 0.f;

  const bool is_att = wg < 128;
  const int wg2 = wg - 128;

  for (int s = 0; s <= 500; ++s) {
    const int sb = s & 1;
    const float* ah_prev = sb ? p.ah0 : p.ah1;
    float*       ah_cur  = sb ? p.ah1 : p.ah0;
    float*       dh_out  = sb ? p.dh0 : p.dh1;
    const float* ctx_prev = sb ? p.ctx0 : p.ctx1;
    float*       ctx_cur  = sb ? p.ctx1 : p.ctx0;
    const unsigned short* ahb_prev  = sb ? p.ahb0 : p.ahb1;
    unsigned short*       ahb_cur   = sb ? p.ahb1 : p.ahb0;
    const unsigned short* dhb_prev2 = sb ? p.dhb1 : p.dhb0;
    unsigned short*       dhb_out   = sb ? p.dhb0 : p.dhb1;
    const unsigned short* ctxb_prev = sb ? p.ctxb0 : p.ctxb1;
    unsigned short*       ctxb_cur  = sb ? p.ctxb1 : p.ctxb0;

    const bool gemm_on = is_att ? (s < 500) : (s >= 1);

    // ================= Phase X: both LSTM gate GEMMs via MFMA =================
    if (gemm_on) {
      const int Tb  = (is_att ? wg : wg2) * 2;
      const int NC  = is_att ? 56 : 80;
      const int cpw = is_att ? 7 : 10;
      const unsigned short* wp = is_att ? p.wpa : p.wpd;
      const int arow = lane & 15;
      const int kgrp = (lane >> 4) * 8;
      f32x4 acc00 = {0,0,0,0}, acc01 = {0,0,0,0}, acc10 = {0,0,0,0}, acc11 = {0,0,0,0};
      for (int i = 0; i < cpw; ++i) {
        const int c = v * cpw + i;
        const unsigned short* ab; int stride, k0;
        if (is_att) {
          if (c < 8)       { ab = p.pre_bf + (size_t)s * 32 * 256; stride = 256;  k0 = c * 32; }
          else if (c < 24) { ab = ctxb_prev;                        stride = 512;  k0 = c * 32 - 256; }
          else             { ab = ahb_prev;                         stride = 1024; k0 = c * 32 - 768; }
        } else {
          if (c < 32)      { ab = ahb_prev;                         stride = 1024; k0 = c * 32; }
          else if (c < 48) { ab = ctxb_prev;                        stride = 512;  k0 = c * 32 - 1024; }
          else             { ab = dhb_prev2;                        stride = 1024; k0 = c * 32 - 1536; }
        }
        const unsigned short* ap = ab + (size_t)arow * stride + k0 + kgrp;
        bf16x8 a0 = *(const bf16x8*)ap;
        bf16x8 a1 = *(const bf16x8*)(ap + 16 * stride);
        const unsigned short* bp = wp + ((size_t)(Tb * NC + c) * 64 + lane) * 8;
        bf16x8 b0 = *(const bf16x8*)bp;
        bf16x8 b1 = *(const bf16x8*)(bp + (size_t)NC * 64 * 8);
        acc00 = __builtin_amdgcn_mfma_f32_16x16x32_bf16(a0, b0, acc00, 0, 0, 0);
        acc01 = __builtin_amdgcn_mfma_f32_16x16x32_bf16(a1, b0, acc01, 0, 0, 0);
        acc10 = __builtin_amdgcn_mfma_f32_16x16x32_bf16(a0, b1, acc10, 0, 0, 0);
        acc11 = __builtin_amdgcn_mfma_f32_16x16x32_bf16(a1, b1, acc11, 0, 0, 0);
      }
      const int po = (lane & 15) * 16 + (lane >> 4) * 4;
      *(f32x4*)&pl[v * 1024 +   0 + po] = acc00;  // tile0, rows 0..15
      *(f32x4*)&pl[v * 1024 + 256 + po] = acc01;  // tile0, rows 16..31
      *(f32x4*)&pl[v * 1024 + 512 + po] = acc10;  // tile1, rows 0..15
      *(f32x4*)&pl[v * 1024 + 768 + po] = acc11;  // tile1, rows 16..31
    }
    __syncthreads();
    if (gemm_on) {
      const float* bias = is_att ? p.ba : p.bd;
      const int nb32 = (is_att ? wg : wg2) * 32;
#pragma unroll
      for (int half = 0; half < 2; ++half) {
        int o = half * 512 + tid;
        float acc = 0.f;
#pragma unroll
        for (int w = 0; w < 8; ++w) acc += pl[w * 1024 + o];
        int rt = (o >> 8) & 1, col = (o >> 4) & 15, row = o & 15;
        int n_local = half * 16 + col;
        int b = rt * 16 + row;
        gates[n_local * 33 + b] = acc + bias[nb32 + n_local];
      }
    }
    __syncthreads();
    if (gemm_on && tid < 256) {
      int u_local = tid >> 5, b = tid & 31;
      float gi = gates[(u_local * 4 + 0) * 33 + b];
      float gf = gates[(u_local * 4 + 1) * 33 + b];
      float gg = gates[(u_local * 4 + 2) * 33 + b];
      float go = gates[(u_local * 4 + 3) * 33 + b];
      float I = sigf(gi), F = sigf(gf), G = tanh_fast(gg), O = sigf(go);
      float c2 = F * cst[tid] + I * G;
      float h = O * tanh_fast(c2);
      cst[tid] = c2;
      if (is_att) {
        int u = wg * 8 + u_local;
        unsigned e = ((unsigned)s * 32 + b) * 1024u + u;
        float mv = ((p.mma[e >> 5] >> (e & 31)) & 1u) ? (1.f / 0.9f) : 0.f;
        float hv = h * mv;
        ah_cur[b * 1024 + u] = hv;
        ahb_cur[b * 1024 + u] = f2bf(hv);
      } else {
        int u = wg2 * 8 + u_local;
        unsigned e = ((unsigned)(s - 1) * 32 + b) * 1024u + u;
        float mv = ((p.mmd[e >> 5] >> (e & 31)) & 1u) ? (1.f / 0.9f) : 0.f;
        float hv = h * mv;
        dh_out[b * 1024 + u] = hv;
        dhb_out[b * 1024 + u] = f2bf(hv);
      }
    }
    // location conv + dense for step s (att WGs; 4 WGs per batch row)
    if (is_att && s < 500) {
      int b = wg >> 2, part = wg & 3;
#pragma unroll
      for (int i2 = 0; i2 < 4; ++i2) {
        int oo = tid + i2 * 512;
        int f = oo >> 6, tt = oo & 63, t = part * 64 + tt;
        const float* wf = p.lcw + f * 62;
        float acc = 0.f;
        for (int k = 0; k < 31; ++k) {
          int ts = t + k - 15;
          if (ts >= 0 && ts < 256)
            acc += p.aw[b * 256 + ts] * wf[k] + p.awcum[b * 256 + ts] * wf[31 + k];
        }
        locT[f * 65 + tt] = acc;
      }
      __syncthreads();
#pragma unroll
      for (int i2 = 0; i2 < 16; ++i2) {
        int oo = tid + i2 * 512;
        int a = oo & 127, tq = oo >> 7;
        int t = part * 64 + tq;
        float val = 0.f;
#pragma unroll
        for (int f = 0; f < 32; ++f) val += locT[f * 65 + tq] * p.ldwt[f * 128 + a];
        p.loc2_bf[((size_t)b * 256 + t) * 128 + a] = f2bf(val);
      }
    }

    grid.sync();

    // ================= Phase B =================
    if (wg < 32) {
      if (s < 500) {
        const int b = wg;
        {
          int a = tid & 127, kq = tid >> 7;
          const float* ahp = ah_cur + b * 1024 + kq * 256;
          const unsigned short* qp = p.qw_bf + (size_t)a * 1024 + kq * 256;
          float acc = 0.f;
          for (int j = 0; j < 256; j += 8) {
            bf16x8 qv = *(const bf16x8*)(qp + j);
            float4 x0 = LD4(ahp + j), x1 = LD4(ahp + j + 4);
            acc += x0.x * bf2f((unsigned short)qv[0]) + x0.y * bf2f((unsigned short)qv[1])
                 + x0.z * bf2f((unsigned short)qv[2]) + x0.w * bf2f((unsigned short)qv[3]);
            acc += x1.x * bf2f((unsigned short)qv[4]) + x1.y * bf2f((unsigned short)qv[5])
                 + x1.z * bf2f((unsigned short)qv[6]) + x1.w * bf2f((unsigned short)qv[7]);
          }
          sm[256 + kq * 128 + a] = acc;
          if (tid < 128) sm[128 + tid] = p.vw[tid];
        }
        __syncthreads();
        if (tid < 128) sm[tid] = sm[256 + tid] + sm[384 + tid] + sm[512 + tid] + sm[640 + tid];
        __syncthreads();
        {
          int t = tid & 255, h2 = tid >> 8;
          const unsigned short* l2p = p.loc2_bf + ((size_t)b * 256 + t) * 128 + h2 * 64;
          const unsigned short* pmp = p.pm_bf   + ((size_t)b * 256 + t) * 128 + h2 * 64;
          float e = 0.f;
          for (int kk = 0; kk < 64; kk += 8) {
            bf16x8 lv = *(const bf16x8*)(l2p + kk);
            bf16x8 pv = *(const bf16x8*)(pmp + kk);
            int a0 = h2 * 64 + kk;
#pragma unroll
            for (int j = 0; j < 8; ++j)
              e += tanh_fast(sm[a0 + j] + bf2f((unsigned short)lv[j]) + bf2f((unsigned short)pv[j])) * sm[128 + a0 + j];
          }
          sm[256 + h2 * 256 + t] = e;
        }
        __syncthreads();
        if (tid < 256) {
          float en = sm[256 + tid] + sm[512 + tid];
          float w = (tid < p.mlen[b]) ? __expf(en) : 0.f;
          sm[768 + tid] = w;
        }
        __syncthreads();
        if (tid < 32) {
          float sub = 0.f;
          for (int i = 0; i < 8; ++i) sub += sm[768 + tid * 8 + i];
          sm[256 + tid] = sub;
        }
        __syncthreads();
        if (tid == 0) {
          float S = 0.f;
          for (int i = 0; i < 32; ++i) S += sm[256 + i];
          sm[1281] = 1.f / S;
        }
        __syncthreads();
        if (tid < 256) {
          float awv = sm[768 + tid] * sm[1281];
          p.aw[b * 256 + tid] = awv;
          p.awcum[b * 256 + tid] += awv;
          p.out[(size_t)AOFF + (size_t)b * 128000 + (size_t)s * 256 + tid] = awv;
          sm[1024 + tid] = awv;
        }
        __syncthreads();
        {
          const unsigned short* mb = p.mem_bf + (size_t)b * 131072 + tid;
          float acc = 0.f;
#pragma unroll 4
          for (int t2 = 0; t2 < 256; ++t2) acc += sm[1024 + t2] * bf2f(mb[(size_t)t2 * 512]);
          ctx_cur[b * 512 + tid] = acc;
          ctxb_cur[b * 512 + tid] = f2bf(acc);
        }
      }
    } else {
      if (s >= 1) {
        int idx = wg - 32;
        int b = idx / 7, c7 = idx % 7;
        int m0 = c7 * 12, mc = (c7 == 6) ? 8 : 12;
        const float* dhb = dh_out + b * 1024;
        const float* cxb = ctx_prev + b * 512;
        int mi = tid >> 5, kg = tid & 31;
        if (mi < mc) {
          int m = m0 + mi;
          const float* pw = p.pjw + (size_t)m * 1536 + kg * 48;
          float acc = 0.f;
          for (int j = 0; j < 48; ++j) {
            int k = kg * 48 + j;
            float x = (k < 1024) ? dhb[k] : cxb[k - 1024];
            acc += x * pw[j];
          }
          sm[mi * 32 + kg] = acc;
        }
        if (c7 == 6 && tid >= 384) {
          int kg2 = tid - 384;
          const float* gwp = p.gw + kg2 * 12;
          float acc = 0.f;
          for (int j = 0; j < 12; ++j) {
            int k = kg2 * 12 + j;
            float x = (k < 1024) ? dhb[k] : cxb[k - 1024];
            acc += x * gwp[j];
          }
          sm[512 + kg2] = acc;
        }
        __syncthreads();
        if (tid < mc) {
          float r = p.pjb[m0 + tid];
          for (int j = 0; j < 32; ++j) r += sm[tid * 32 + j];
          p.out[(size_t)b * 40000 + (size_t)(m0 + tid) * 500 + (s - 1)] = r;
        }
        if (c7 == 6 && tid == 384) {
          float r = p.gb[0];
          for (int j = 0; j < 128; ++j) r += sm[512 + j];
          p.out[(size_t)GOFF + (size_t)b * 500 + (s - 1)] = r;
        }
      }
    }

    grid.sync();
  }
}

// ---------------- host ----------------
extern "C" void kernel_launch(void* const* d_in, const int* in_sizes, int n_in,
                              void* d_out, int out_size, void* d_ws, size_t ws_size,
                              hipStream_t stream) {
  Params p;
  p.memory = (const float*)d_in[0];
  p.dec_in = (const float*)d_in[1];
  p.mlen   = (const int*)d_in[2];
  p.pw1  = (const float*)d_in[3];
  p.pw2  = (const float*)d_in[4];
  p.awih = (const float*)d_in[5];
  p.awhh = (const float*)d_in[6];
  p.abih = (const float*)d_in[7];
  p.abhh = (const float*)d_in[8];
  p.qw   = (const float*)d_in[9];
  p.mw   = (const float*)d_in[10];
  p.vw   = (const float*)d_in[11];
  p.lcw  = (const float*)d_in[12];
  p.ldw  = (const float*)d_in[13];
  p.dwih = (const float*)d_in[14];
  p.dwhh = (const float*)d_in[15];
  p.dbih = (const float*)d_in[16];
  p.dbhh = (const float*)d_in[17];
  p.pjw  = (const float*)d_in[18];
  p.pjb  = (const float*)d_in[19];
  p.gw   = (const float*)d_in[20];
  p.gb   = (const float*)d_in[21];
  p.out  = (float*)d_out;

  char* cur = (char*)d_ws;
  auto allocf = [&](size_t n) { float* r = (float*)cur; cur += n * sizeof(float); return r; };
  auto allocs = [&](size_t n) { unsigned short* r = (unsigned short*)cur; cur += n * sizeof(unsigned short); return r; };
  // state (memset once)
  p.ah0 = allocf(32 * 1024); p.ah1 = allocf(32 * 1024);
  p.dh0 = allocf(32 * 1024); p.dh1 = allocf(32 * 1024);
  p.ctx0 = allocf(32 * 512); p.ctx1 = allocf(32 * 512);
  p.aw = allocf(32 * 256); p.awcum = allocf(32 * 256);
  p.ahb0 = allocs(32 * 1024); p.ahb1 = allocs(32 * 1024);
  p.dhb0 = allocs(32 * 1024); p.dhb1 = allocs(32 * 1024);
  p.ctxb0 = allocs(32 * 512); p.ctxb1 = allocs(32 * 512);
  size_t state_bytes = (size_t)(cur - (char*)d_ws);
  // static
  p.x1   = allocf((size_t)500 * 32 * 256);
  p.w1t  = allocf(80 * 256);
  p.w2t  = allocf(256 * 256);
  p.mwt  = allocf(512 * 128);
  p.ldwt = allocf(32 * 128);
  p.ba   = allocf(4096);
  p.bd   = allocf(4096);
  p.pre_bf  = allocs((size_t)500 * 32 * 256);
  p.pm_bf   = allocs((size_t)32 * 256 * 128);
  p.loc2_bf = allocs((size_t)32 * 256 * 128);
  p.mem_bf  = allocs((size_t)32 * 256 * 512);
  p.qw_bf   = allocs(128 * 1024);
  p.wpa     = allocs((size_t)256 * 56 * 64 * 8);
  p.wpd     = allocs((size_t)256 * 80 * 64 * 8);
  p.mma = (unsigned*)cur; cur += 512000u * 4;
  p.mmd = (unsigned*)cur; cur += 512000u * 4;
  p.mm1 = (unsigned*)cur; cur += 128256u * 4;
  p.mm2 = (unsigned*)cur; cur += 128256u * 4;

  (void)hipMemsetAsync(d_ws, 0, state_bytes, stream);

  unsigned k[8];
  {
    unsigned o0, o1;
    tf_block(0u, 1u, 0u, 0u, o0, o1); k[0] = o0; k[1] = o1;
    tf_block(0u, 1u, 0u, 1u, o0, o1); k[2] = o0; k[3] = o1;
    tf_block(0u, 1u, 0u, 2u, o0, o1); k[4] = o0; k[5] = o1;
    tf_block(0u, 1u, 0u, 3u, o0, o1); k[6] = o0; k[7] = o1;
  }

  maskgen_kernel<<<(1280512 + 255) / 256, 256, 0, stream>>>(p, k[0], k[1], k[2], k[3], k[4], k[5], k[6], k[7]);
  prep_misc<<<(4489216 + 255) / 256, 256, 0, stream>>>(p);
  pack_att<<<(917504 + 255) / 256, 256, 0, stream>>>(p);
  pack_dec<<<(1310720 + 255) / 256, 256, 0, stream>>>(p);
  prenet1_kernel<<<2000, 256, 0, stream>>>(p);
  prenet2_kernel<<<2000, 256, 0, stream>>>(p);
  pm_kernel<<<512, 128, 0, stream>>>(p);

  void* args[] = { (void*)&p };
  (void)hipLaunchCooperativeKernel((const void*)scan_kernel, dim3(256), dim3(512), args, 0, stream);
}

// Round 4
// 94724.475 us; speedup vs baseline: 1.8514x; 1.0033x over previous
//
#include <hip/hip_runtime.h>
#include <hip/hip_cooperative_groups.h>
#include <math.h>
#include <string.h>

namespace cg = cooperative_groups;

#define TOUT 500
#define AOFF 1296000
#define GOFF 1280000
#define TF_BITS_XOR 1

typedef float f32x4 __attribute__((ext_vector_type(4)));
typedef short bf16x8 __attribute__((ext_vector_type(8)));

struct Params {
  const float *memory, *dec_in, *pw1, *pw2, *awih, *awhh, *abih, *abhh;
  const float *qw, *mw, *vw, *lcw, *ldw, *dwih, *dwhh, *dbih, *dbhh;
  const float *pjw, *pjb, *gw, *gb;
  const int* mlen;
  float* out;
  // fp32 state
  float *ah0, *ah1, *dh0, *dh1, *ctx0, *ctx1, *aw, *awcum;
  // bf16 state mirrors
  unsigned short *ahb0, *ahb1, *dhb0, *dhb1, *ctxb0, *ctxb1;
  // static fp32
  float *x1, *w1t, *w2t, *mwt, *ldwt, *ba, *bd;
  // static bf16
  unsigned short *pre_bf, *pm_bf, *loc2_bf, *mem_bf, *qw_bf, *wpa, *wpd;
  unsigned *mma, *mmd, *mm1, *mm2;
};

// ---------------- threefry2x32 (matches jax partitionable path) ----------------
__host__ __device__ inline void tf_block(unsigned k0, unsigned k1, unsigned x0, unsigned x1,
                                         unsigned& o0, unsigned& o1) {
  unsigned ks2 = k0 ^ k1 ^ 0x1BD11BDAu;
  x0 += k0; x1 += k1;
#define TFR(r) { x0 += x1; x1 = (x1 << r) | (x1 >> (32 - r)); x1 ^= x0; }
  TFR(13) TFR(15) TFR(26) TFR(6)
  x0 += k1;  x1 += ks2 + 1u;
  TFR(17) TFR(29) TFR(16) TFR(24)
  x0 += ks2; x1 += k0 + 2u;
  TFR(13) TFR(15) TFR(26) TFR(6)
  x0 += k0;  x1 += k1 + 3u;
  TFR(17) TFR(29) TFR(16) TFR(24)
  x0 += k1;  x1 += ks2 + 4u;
  TFR(13) TFR(15) TFR(26) TFR(6)
  x0 += ks2; x1 += k0 + 5u;
#undef TFR
  o0 = x0; o1 = x1;
}

__device__ inline float sigf(float x) { return 1.f / (1.f + __expf(-x)); }
__device__ inline float tanh_fast(float x) {
  float ax = fabsf(x);
  float t = __expf(-2.f * ax);
  float r = (1.f - t) / (1.f + t);
  return copysignf(r, x);
}
__device__ inline unsigned short f2bf(float f) {
  unsigned u = __float_as_uint(f);
  unsigned r = (u + 0x7FFFu + ((u >> 16) & 1u)) >> 16;
  return (unsigned short)r;
}
__device__ inline float bf2f(unsigned short u) {
  return __uint_as_float((unsigned)u << 16);
}

#define LD4(p) (*(const float4*)(p))

// ---------------- mask generation (bit-packed) ----------------
__global__ void maskgen_kernel(Params p, unsigned k1a, unsigned k1b, unsigned k2a, unsigned k2b,
                               unsigned k3a, unsigned k3b, unsigned k4a, unsigned k4b) {
  int t = blockIdx.x * 256 + threadIdx.x;
  unsigned ka, kb; unsigned* dst; float pp;
  if (t < 512000)       { ka = k3a; kb = k3b; dst = p.mma; pp = 0.9f; }
  else if (t < 1024000) { t -= 512000;  ka = k4a; kb = k4b; dst = p.mmd; pp = 0.9f; }
  else if (t < 1152256) { t -= 1024000; ka = k1a; kb = k1b; dst = p.mm1; pp = 0.5f; }
  else if (t < 1280512) { t -= 1152256; ka = k2a; kb = k2b; dst = p.mm2; pp = 0.5f; }
  else return;
  unsigned word = 0u;
  for (int i = 0; i < 32; ++i) {
    unsigned o0, o1;
    tf_block(ka, kb, 0u, (unsigned)t * 32u + (unsigned)i, o0, o1);
#if TF_BITS_XOR
    unsigned bits = o0 ^ o1;
#else
    unsigned bits = o0;
#endif
    unsigned fb = (bits >> 9) | 0x3f800000u;
    float u = __uint_as_float(fb) - 1.0f;
    if (u < pp) word |= (1u << i);
  }
  dst[t] = word;
}

// ---------------- misc static prep ----------------
__global__ void prep_misc(Params p) {
  int i = blockIdx.x * 256 + threadIdx.x;
  if (i < 20480) { int k = i >> 8, u = i & 255; p.w1t[i] = p.pw1[u * 80 + k]; return; }
  i -= 20480;
  if (i < 65536) { int k = i >> 8, u = i & 255; p.w2t[i] = p.pw2[u * 256 + k]; return; }
  i -= 65536;
  if (i < 65536) { int k = i >> 7, a = i & 127; p.mwt[i] = p.mw[a * 512 + k]; return; }
  i -= 65536;
  if (i < 131072) { p.qw_bf[i] = f2bf(p.qw[i]); return; }
  i -= 131072;
  if (i < 4096) { int f = i >> 7, a = i & 127; p.ldwt[i] = p.ldw[a * 32 + f]; return; }
  i -= 4096;
  if (i < 4096) { int col = (i & 3) * 1024 + (i >> 2); p.ba[i] = p.abih[col] + p.abhh[col]; return; }
  i -= 4096;
  if (i < 4096) { int col = (i & 3) * 1024 + (i >> 2); p.bd[i] = p.dbih[col] + p.dbhh[col]; return; }
  i -= 4096;
  if (i < 4194304) { p.mem_bf[i] = f2bf(p.memory[i]); return; }
}

// ---------------- weight packing into MFMA B-fragment order ----------------
// wpa[T][c][lane][8]: B[k=32c+8*(lane>>4)+j][n=T*16+(lane&15)], col = (n&3)*1024 + (n>>2)
__global__ void pack_att(Params p) {
  int idx = blockIdx.x * 256 + threadIdx.x;
  if (idx >= 256 * 56 * 64) return;
  int l = idx & 63;
  int c = (idx >> 6) % 56;
  int T = idx / (56 * 64);
  int n = T * 16 + (l & 15);
  int col = (n & 3) * 1024 + (n >> 2);
  int kb = c * 32 + 8 * (l >> 4);
  bf16x8 v;
#pragma unroll
  for (int j = 0; j < 8; ++j) {
    int k = kb + j;
    float f = (k < 768) ? p.awih[(size_t)col * 768 + k] : p.awhh[(size_t)col * 1024 + k - 768];
    v[j] = (short)f2bf(f);
  }
  *(bf16x8*)(p.wpa + (size_t)idx * 8) = v;
}
__global__ void pack_dec(Params p) {
  int idx = blockIdx.x * 256 + threadIdx.x;
  if (idx >= 256 * 80 * 64) return;
  int l = idx & 63;
  int c = (idx >> 6) % 80;
  int T = idx / (80 * 64);
  int n = T * 16 + (l & 15);
  int col = (n & 3) * 1024 + (n >> 2);
  int kb = c * 32 + 8 * (l >> 4);
  bf16x8 v;
#pragma unroll
  for (int j = 0; j < 8; ++j) {
    int k = kb + j;
    float f = (k < 1536) ? p.dwih[(size_t)col * 1536 + k] : p.dwhh[(size_t)col * 1024 + k - 1536];
    v[j] = (short)f2bf(f);
  }
  *(bf16x8*)(p.wpd + (size_t)idx * 8) = v;
}

// ---------------- prenet ----------------
__global__ void prenet1_kernel(Params p) {
  __shared__ float din[8][80];
  int wg = blockIdx.x, tid = threadIdx.x;
  int r0 = wg * 8;
  for (int idx = tid; idx < 8 * 80; idx += 256) {
    int j = idx / 80, kk = idx % 80;
    int r = r0 + j; int t = r >> 5, b = r & 31;
    din[j][kk] = (t == 0) ? 0.f : p.dec_in[(size_t)b * 40000 + (size_t)kk * 500 + (t - 1)];
  }
  __syncthreads();
  float acc[8] = {0,0,0,0,0,0,0,0};
  for (int k = 0; k < 80; ++k) {
    float wv = p.w1t[k * 256 + tid];
#pragma unroll
    for (int j = 0; j < 8; ++j) acc[j] += din[j][k] * wv;
  }
  for (int j = 0; j < 8; ++j) {
    int r = r0 + j;
    unsigned e = (unsigned)r * 256u + tid;
    float mv = ((p.mm1[e >> 5] >> (e & 31)) & 1u) ? 2.0f : 0.0f;
    p.x1[(size_t)r * 256 + tid] = fmaxf(acc[j], 0.f) * mv;
  }
}
__global__ void prenet2_kernel(Params p) {
  __shared__ float rows[8][256];
  int wg = blockIdx.x, tid = threadIdx.x;
  int r0 = wg * 8;
  for (int idx = tid; idx < 8 * 256; idx += 256) {
    int j = idx >> 8, kk = idx & 255;
    rows[j][kk] = p.x1[(size_t)(r0 + j) * 256 + kk];
  }
  __syncthreads();
  float acc[8] = {0,0,0,0,0,0,0,0};
  for (int k = 0; k < 256; ++k) {
    float wv = p.w2t[k * 256 + tid];
#pragma unroll
    for (int j = 0; j < 8; ++j) acc[j] += rows[j][k] * wv;
  }
  for (int j = 0; j < 8; ++j) {
    int r = r0 + j;
    unsigned e = (unsigned)r * 256u + tid;
    float mv = ((p.mm2[e >> 5] >> (e & 31)) & 1u) ? 2.0f : 0.0f;
    p.pre_bf[(size_t)r * 256 + tid] = f2bf(fmaxf(acc[j], 0.f) * mv);
  }
}

// ---------------- processed_memory -> bf16 ----------------
__global__ void pm_kernel(Params p) {
  __shared__ float mrows[16][512];
  int wg = blockIdx.x;
  int b = wg >> 4, tc = wg & 15;
  int tid = threadIdx.x;
  int t0 = tc * 16;
  for (int idx = tid; idx < 16 * 512; idx += 128) {
    int i = idx >> 9, k = idx & 511;
    mrows[i][k] = p.memory[((size_t)b * 256 + t0 + i) * 512 + k];
  }
  __syncthreads();
  float acc[16];
#pragma unroll
  for (int i = 0; i < 16; ++i) acc[i] = 0.f;
  for (int k = 0; k < 512; ++k) {
    float wv = p.mwt[k * 128 + tid];
#pragma unroll
    for (int i = 0; i < 16; ++i) acc[i] += mrows[i][k] * wv;
  }
  for (int i = 0; i < 16; ++i)
    p.pm_bf[((size_t)b * 256 + t0 + i) * 128 + tid] = f2bf(acc[i]);
}

// ---------------- GEMM: two 16-col tiles per WG, fully unrolled, B-frags prefetched ----------------
// pl layout: pl[v*1088 + sub*272 + n*17 + brow], sub = tile*2+half
template<int NC, int CPW, bool ATT>
__device__ __forceinline__ void gemm_tile2(const Params& p, int Tb, int lane, int v, int s,
                                           const unsigned short* ctxb_prev,
                                           const unsigned short* ahb_prev,
                                           const unsigned short* dhb_prev2,
                                           float* pl) {
  const unsigned short* wp = ATT ? p.wpa : p.wpd;
  const int arow = lane & 15;
  const int kgrp = (lane >> 4) * 8;
  // prefetch ALL weight fragments for this wave: independent loads -> deep MLP
  bf16x8 bfa[CPW], bfb[CPW];
#pragma unroll
  for (int i = 0; i < CPW; ++i) {
    const unsigned short* bp = wp + ((size_t)(Tb * NC + v * CPW + i) * 64 + lane) * 8;
    bfa[i] = *(const bf16x8*)bp;
    bfb[i] = *(const bf16x8*)(bp + (size_t)NC * 64 * 8);
  }
  f32x4 acc00 = {0,0,0,0}, acc01 = {0,0,0,0}, acc10 = {0,0,0,0}, acc11 = {0,0,0,0};
#pragma unroll
  for (int i = 0; i < CPW; ++i) {
    const int c = v * CPW + i;
    const unsigned short* ab; int stride, k0;
    if (ATT) {
      if (c < 8)       { ab = p.pre_bf + (size_t)s * 32 * 256; stride = 256;  k0 = c * 32; }
      else if (c < 24) { ab = ctxb_prev;                        stride = 512;  k0 = c * 32 - 256; }
      else             { ab = ahb_prev;                         stride = 1024; k0 = c * 32 - 768; }
    } else {
      if (c < 32)      { ab = ahb_prev;                         stride = 1024; k0 = c * 32; }
      else if (c < 48) { ab = ctxb_prev;                        stride = 512;  k0 = c * 32 - 1024; }
      else             { ab = dhb_prev2;                        stride = 1024; k0 = c * 32 - 1536; }
    }
    const unsigned short* ap = ab + (size_t)arow * stride + k0 + kgrp;
    bf16x8 a0 = *(const bf16x8*)ap;
    bf16x8 a1 = *(const bf16x8*)(ap + 16 * stride);
    acc00 = __builtin_amdgcn_mfma_f32_16x16x32_bf16(a0, bfa[i], acc00, 0, 0, 0);
    acc01 = __builtin_amdgcn_mfma_f32_16x16x32_bf16(a1, bfa[i], acc01, 0, 0, 0);
    acc10 = __builtin_amdgcn_mfma_f32_16x16x32_bf16(a0, bfb[i], acc10, 0, 0, 0);
    acc11 = __builtin_amdgcn_mfma_f32_16x16x32_bf16(a1, bfb[i], acc11, 0, 0, 0);
  }
  const int po = (lane & 15) * 17 + (lane >> 4) * 4;
#pragma unroll
  for (int j = 0; j < 4; ++j) {
    pl[v * 1088 +   0 + po + j] = acc00[j];
    pl[v * 1088 + 272 + po + j] = acc01[j];
    pl[v * 1088 + 544 + po + j] = acc10[j];
    pl[v * 1088 + 816 + po + j] = acc11[j];
  }
}

// ---------------- persistent cooperative scan kernel ----------------
// 256 WGs x 512. WGs 0..127: att-LSTM (32 cols each) + conv. WGs 128..255: dec-LSTM.
// Phase B: WGs 0..31 attention (1 batch each), 32..255 mel/gate projection.
__global__ void __launch_bounds__(512) scan_kernel(Params p) {
  cg::grid_group grid = cg::this_grid();
  const int wg = blockIdx.x;
  const int tid = threadIdx.x;
  const int lane = tid & 63;
  const int v = tid >> 6;

  __shared__ float pl[8 * 1088];   // 8 waves x 4 subtiles x (16n x 17)
  __shared__ float gates[32 * 33]; // [n_local][b]
  __shared__ float cst[256];       // cell state: 8 units x 32 b
  __shared__ float locT[32 * 65];
  __shared__ float sm[1536];

  if (tid < 256) cst[tid] = 0.f;

  const bool is_att = wg < 128;
  const int wg2 = wg - 128;

  for (int s = 0; s <= 500; ++s) {
    const int sb = s & 1;
    const float* ah_prev = sb ? p.ah0 : p.ah1;
    float*       ah_cur  = sb ? p.ah1 : p.ah0;
    float*       dh_out  = sb ? p.dh0 : p.dh1;
    const float* ctx_prev = sb ? p.ctx0 : p.ctx1;
    float*       ctx_cur  = sb ? p.ctx1 : p.ctx0;
    const unsigned short* ahb_prev  = sb ? p.ahb0 : p.ahb1;
    unsigned short*       ahb_cur   = sb ? p.ahb1 : p.ahb0;
    const unsigned short* dhb_prev2 = sb ? p.dhb1 : p.dhb0;
    unsigned short*       dhb_out   = sb ? p.dhb0 : p.dhb1;
    const unsigned short* ctxb_prev = sb ? p.ctxb0 : p.ctxb1;
    unsigned short*       ctxb_cur  = sb ? p.ctxb1 : p.ctxb0;

    const bool gemm_on = is_att ? (s < 500) : (s >= 1);

    // ================= Phase X =================
    if (gemm_on) {
      if (is_att) gemm_tile2<56, 7, true >(p, wg  * 2, lane, v, s, ctxb_prev, ahb_prev, dhb_prev2, pl);
      else        gemm_tile2<80, 10, false>(p, wg2 * 2, lane, v, s, ctxb_prev, ahb_prev, dhb_prev2, pl);
    }
    __syncthreads();
    if (gemm_on) {
      const float* bias = is_att ? p.ba : p.bd;
      const int nb32 = (is_att ? wg : wg2) * 32;
#pragma unroll
      for (int rep = 0; rep < 2; ++rep) {
        int o = rep * 512 + tid;
        int tile = o >> 9, half = (o >> 8) & 1, n = (o >> 4) & 15, brow = o & 15;
        int o2 = (tile * 2 + half) * 272 + n * 17 + brow;
        float acc = 0.f;
#pragma unroll
        for (int w = 0; w < 8; ++w) acc += pl[w * 1088 + o2];
        int n_local = tile * 16 + n;
        gates[n_local * 33 + half * 16 + brow] = acc + bias[nb32 + n_local];
      }
    }
    __syncthreads();
    if (gemm_on && tid < 256) {
      int u_local = tid >> 5, b = tid & 31;
      float gi = gates[(u_local * 4 + 0) * 33 + b];
      float gf = gates[(u_local * 4 + 1) * 33 + b];
      float gg = gates[(u_local * 4 + 2) * 33 + b];
      float go = gates[(u_local * 4 + 3) * 33 + b];
      float I = sigf(gi), F = sigf(gf), G = tanh_fast(gg), O = sigf(go);
      float c2 = F * cst[tid] + I * G;
      float h = O * tanh_fast(c2);
      cst[tid] = c2;
      if (is_att) {
        int u = wg * 8 + u_local;
        unsigned e = ((unsigned)s * 32 + b) * 1024u + u;
        float mv = ((p.mma[e >> 5] >> (e & 31)) & 1u) ? (1.f / 0.9f) : 0.f;
        float hv = h * mv;
        ah_cur[b * 1024 + u] = hv;
        ahb_cur[b * 1024 + u] = f2bf(hv);
      } else {
        int u = wg2 * 8 + u_local;
        unsigned e = ((unsigned)(s - 1) * 32 + b) * 1024u + u;
        float mv = ((p.mmd[e >> 5] >> (e & 31)) & 1u) ? (1.f / 0.9f) : 0.f;
        float hv = h * mv;
        dh_out[b * 1024 + u] = hv;
        dhb_out[b * 1024 + u] = f2bf(hv);
      }
    }
    // location conv + dense for step s (att WGs; 4 WGs per batch row)
    if (is_att && s < 500) {
      int b = wg >> 2, part = wg & 3;
#pragma unroll
      for (int i2 = 0; i2 < 4; ++i2) {
        int oo = tid + i2 * 512;
        int f = oo >> 6, tt = oo & 63, t = part * 64 + tt;
        const float* wf = p.lcw + f * 62;
        float acc = 0.f;
#pragma unroll
        for (int k = 0; k < 31; ++k) {
          int ts = t + k - 15;
          if (ts >= 0 && ts < 256)
            acc += p.aw[b * 256 + ts] * wf[k] + p.awcum[b * 256 + ts] * wf[31 + k];
        }
        locT[f * 65 + tt] = acc;
      }
      __syncthreads();
#pragma unroll
      for (int i2 = 0; i2 < 16; ++i2) {
        int oo = tid + i2 * 512;
        int a = oo & 127, tq = oo >> 7;
        int t = part * 64 + tq;
        float val = 0.f;
#pragma unroll
        for (int f = 0; f < 32; ++f) val += locT[f * 65 + tq] * p.ldwt[f * 128 + a];
        p.loc2_bf[((size_t)b * 256 + t) * 128 + a] = f2bf(val);
      }
    }

    grid.sync();

    // ================= Phase B =================
    if (wg < 32) {
      if (s < 500) {
        const int b = wg;
        {
          int a = tid & 127, kq = tid >> 7;
          const float* ahp = ah_cur + b * 1024 + kq * 256;
          const unsigned short* qp = p.qw_bf + (size_t)a * 1024 + kq * 256;
          float acc = 0.f;
#pragma unroll 4
          for (int j = 0; j < 256; j += 8) {
            bf16x8 qv = *(const bf16x8*)(qp + j);
            float4 x0 = LD4(ahp + j), x1 = LD4(ahp + j + 4);
            acc += x0.x * bf2f((unsigned short)qv[0]) + x0.y * bf2f((unsigned short)qv[1])
                 + x0.z * bf2f((unsigned short)qv[2]) + x0.w * bf2f((unsigned short)qv[3]);
            acc += x1.x * bf2f((unsigned short)qv[4]) + x1.y * bf2f((unsigned short)qv[5])
                 + x1.z * bf2f((unsigned short)qv[6]) + x1.w * bf2f((unsigned short)qv[7]);
          }
          sm[256 + kq * 128 + a] = acc;
          if (tid < 128) sm[128 + tid] = p.vw[tid];
        }
        __syncthreads();
        if (tid < 128) sm[tid] = sm[256 + tid] + sm[384 + tid] + sm[512 + tid] + sm[640 + tid];
        __syncthreads();
        {
          int t = tid & 255, h2 = tid >> 8;
          const unsigned short* l2p = p.loc2_bf + ((size_t)b * 256 + t) * 128 + h2 * 64;
          const unsigned short* pmp = p.pm_bf   + ((size_t)b * 256 + t) * 128 + h2 * 64;
          float e = 0.f;
#pragma unroll 2
          for (int kk = 0; kk < 64; kk += 8) {
            bf16x8 lv = *(const bf16x8*)(l2p + kk);
            bf16x8 pv = *(const bf16x8*)(pmp + kk);
            int a0 = h2 * 64 + kk;
#pragma unroll
            for (int j = 0; j < 8; ++j)
              e += tanh_fast(sm[a0 + j] + bf2f((unsigned short)lv[j]) + bf2f((unsigned short)pv[j])) * sm[128 + a0 + j];
          }
          sm[256 + h2 * 256 + t] = e;
        }
        __syncthreads();
        if (tid < 256) {
          float en = sm[256 + tid] + sm[512 + tid];
          float w = (tid < p.mlen[b]) ? __expf(en) : 0.f;
          sm[768 + tid] = w;
        }
        __syncthreads();
        if (tid < 32) {
          float sub = 0.f;
#pragma unroll
          for (int i = 0; i < 8; ++i) sub += sm[768 + tid * 8 + i];
          sm[256 + tid] = sub;
        }
        __syncthreads();
        if (tid == 0) {
          float S = 0.f;
#pragma unroll
          for (int i = 0; i < 32; ++i) S += sm[256 + i];
          sm[1281] = 1.f / S;
        }
        __syncthreads();
        if (tid < 256) {
          float awv = sm[768 + tid] * sm[1281];
          p.aw[b * 256 + tid] = awv;
          p.awcum[b * 256 + tid] += awv;
          p.out[(size_t)AOFF + (size_t)b * 128000 + (size_t)s * 256 + tid] = awv;
          sm[1024 + tid] = awv;
        }
        __syncthreads();
        {
          const unsigned short* mb = p.mem_bf + (size_t)b * 131072 + tid;
          float acc = 0.f;
#pragma unroll 8
          for (int t2 = 0; t2 < 256; ++t2) acc += sm[1024 + t2] * bf2f(mb[(size_t)t2 * 512]);
          ctx_cur[b * 512 + tid] = acc;
          ctxb_cur[b * 512 + tid] = f2bf(acc);
        }
      }
    } else {
      if (s >= 1) {
        int idx = wg - 32;
        int b = idx / 7, c7 = idx % 7;
        int m0 = c7 * 12, mc = (c7 == 6) ? 8 : 12;
        const float* dhb = dh_out + b * 1024;
        const float* cxb = ctx_prev + b * 512;
        int mi = tid >> 5, kg = tid & 31;
        if (mi < mc) {
          int m = m0 + mi;
          const float* pw = p.pjw + (size_t)m * 1536 + kg * 48;
          float acc = 0.f;
#pragma unroll 4
          for (int j = 0; j < 48; ++j) {
            int k = kg * 48 + j;
            float x = (k < 1024) ? dhb[k] : cxb[k - 1024];
            acc += x * pw[j];
          }
          sm[mi * 32 + kg] = acc;
        }
        if (c7 == 6 && tid >= 384) {
          int kg2 = tid - 384;
          const float* gwp = p.gw + kg2 * 12;
          float acc = 0.f;
#pragma unroll
          for (int j = 0; j < 12; ++j) {
            int k = kg2 * 12 + j;
            float x = (k < 1024) ? dhb[k] : cxb[k - 1024];
            acc += x * gwp[j];
          }
          sm[512 + kg2] = acc;
        }
        __syncthreads();
        if (tid < mc) {
          float r = p.pjb[m0 + tid];
#pragma unroll
          for (int j = 0; j < 32; ++j) r += sm[tid * 32 + j];
          p.out[(size_t)b * 40000 + (size_t)(m0 + tid) * 500 + (s - 1)] = r;
        }
        if (c7 == 6 && tid == 384) {
          float r = p.gb[0];
#pragma unroll
          for (int j = 0; j < 128; ++j) r += sm[512 + j];
          p.out[(size_t)GOFF + (size_t)b * 500 + (s - 1)] = r;
        }
      }
    }

    grid.sync();
  }
}

// ---------------- host ----------------
extern "C" void kernel_launch(void* const* d_in, const int* in_sizes, int n_in,
                              void* d_out, int out_size, void* d_ws, size_t ws_size,
                              hipStream_t stream) {
  Params p;
  p.memory = (const float*)d_in[0];
  p.dec_in = (const float*)d_in[1];
  p.mlen   = (const int*)d_in[2];
  p.pw1  = (const float*)d_in[3];
  p.pw2  = (const float*)d_in[4];
  p.awih = (const float*)d_in[5];
  p.awhh = (const float*)d_in[6];
  p.abih = (const float*)d_in[7];
  p.abhh = (const float*)d_in[8];
  p.qw   = (const float*)d_in[9];
  p.mw   = (const float*)d_in[10];
  p.vw   = (const float*)d_in[11];
  p.lcw  = (const float*)d_in[12];
  p.ldw  = (const float*)d_in[13];
  p.dwih = (const float*)d_in[14];
  p.dwhh = (const float*)d_in[15];
  p.dbih = (const float*)d_in[16];
  p.dbhh = (const float*)d_in[17];
  p.pjw  = (const float*)d_in[18];
  p.pjb  = (const float*)d_in[19];
  p.gw   = (const float*)d_in[20];
  p.gb   = (const float*)d_in[21];
  p.out  = (float*)d_out;

  char* cur = (char*)d_ws;
  auto allocf = [&](size_t n) { float* r = (float*)cur; cur += n * sizeof(float); return r; };
  auto allocs = [&](size_t n) { unsigned short* r = (unsigned short*)cur; cur += n * sizeof(unsigned short); return r; };
  p.ah0 = allocf(32 * 1024); p.ah1 = allocf(32 * 1024);
  p.dh0 = allocf(32 * 1024); p.dh1 = allocf(32 * 1024);
  p.ctx0 = allocf(32 * 512); p.ctx1 = allocf(32 * 512);
  p.aw = allocf(32 * 256); p.awcum = allocf(32 * 256);
  p.ahb0 = allocs(32 * 1024); p.ahb1 = allocs(32 * 1024);
  p.dhb0 = allocs(32 * 1024); p.dhb1 = allocs(32 * 1024);
  p.ctxb0 = allocs(32 * 512); p.ctxb1 = allocs(32 * 512);
  size_t state_bytes = (size_t)(cur - (char*)d_ws);
  p.x1   = allocf((size_t)500 * 32 * 256);
  p.w1t  = allocf(80 * 256);
  p.w2t  = allocf(256 * 256);
  p.mwt  = allocf(512 * 128);
  p.ldwt = allocf(32 * 128);
  p.ba   = allocf(4096);
  p.bd   = allocf(4096);
  p.pre_bf  = allocs((size_t)500 * 32 * 256);
  p.pm_bf   = allocs((size_t)32 * 256 * 128);
  p.loc2_bf = allocs((size_t)32 * 256 * 128);
  p.mem_bf  = allocs((size_t)32 * 256 * 512);
  p.qw_bf   = allocs(128 * 1024);
  p.wpa     = allocs((size_t)256 * 56 * 64 * 8);
  p.wpd     = allocs((size_t)256 * 80 * 64 * 8);
  p.mma = (unsigned*)cur; cur += 512000u * 4;
  p.mmd = (unsigned*)cur; cur += 512000u * 4;
  p.mm1 = (unsigned*)cur; cur += 128256u * 4;
  p.mm2 = (unsigned*)cur; cur += 128256u * 4;

  (void)hipMemsetAsync(d_ws, 0, state_bytes, stream);

  unsigned k[8];
  {
    unsigned o0, o1;
    tf_block(0u, 1u, 0u, 0u, o0, o1); k[0] = o0; k[1] = o1;
    tf_block(0u, 1u, 0u, 1u, o0, o1); k[2] = o0; k[3] = o1;
    tf_block(0u, 1u, 0u, 2u, o0, o1); k[4] = o0; k[5] = o1;
    tf_block(0u, 1u, 0u, 3u, o0, o1); k[6] = o0; k[7] = o1;
  }

  maskgen_kernel<<<(1280512 + 255) / 256, 256, 0, stream>>>(p, k[0], k[1], k[2], k[3], k[4], k[5], k[6], k[7]);
  prep_misc<<<(4489216 + 255) / 256, 256, 0, stream>>>(p);
  pack_att<<<(917504 + 255) / 256, 256, 0, stream>>>(p);
  pack_dec<<<(1310720 + 255) / 256, 256, 0, stream>>>(p);
  prenet1_kernel<<<2000, 256, 0, stream>>>(p);
  prenet2_kernel<<<2000, 256, 0, stream>>>(p);
  pm_kernel<<<512, 128, 0, stream>>>(p);

  void* args[] = { (void*)&p };
  (void)hipLaunchCooperativeKernel((const void*)scan_kernel, dim3(256), dim3(512), args, 0, stream);
}

// Round 6
// 57489.270 us; speedup vs baseline: 3.0506x; 1.6477x over previous
//
#include <hip/hip_runtime.h>
#include <math.h>
#include <string.h>

#define TOUT 500
#define AOFF 1296000
#define GOFF 1280000
#define TF_BITS_XOR 1

typedef float f32x4 __attribute__((ext_vector_type(4)));
typedef short bf16x8 __attribute__((ext_vector_type(8)));
typedef unsigned short ushort4_t __attribute__((ext_vector_type(4)));

struct Params {
  const float *memory, *dec_in, *pw1, *pw2, *awih, *awhh, *abih, *abhh;
  const float *qw, *mw, *vw, *lcw, *ldw, *dwih, *dwhh, *dbih, *dbhh;
  const float *pjw, *pjb, *gw, *gb;
  const int* mlen;
  float* out;
  // mutable cross-WG state (bf16), memset each launch
  unsigned short *ahb0, *ahb1, *dhb0, *dhb1, *ctxb0, *ctxb1;
  unsigned *barc;   // [2]
  unsigned *barg;   // [1]
  // static precomputed
  float *x1, *w1t, *w2t, *mwt, *ldwt, *ba, *bd;
  unsigned short *pre_bf, *pm_bf, *mem_bf, *qw_bf, *wpa, *wpd;
  unsigned *mma, *mmd, *mm1, *mm2;
};

// ---------------- threefry2x32 (matches jax partitionable path) ----------------
__host__ __device__ inline void tf_block(unsigned k0, unsigned k1, unsigned x0, unsigned x1,
                                         unsigned& o0, unsigned& o1) {
  unsigned ks2 = k0 ^ k1 ^ 0x1BD11BDAu;
  x0 += k0; x1 += k1;
#define TFR(r) { x0 += x1; x1 = (x1 << r) | (x1 >> (32 - r)); x1 ^= x0; }
  TFR(13) TFR(15) TFR(26) TFR(6)
  x0 += k1;  x1 += ks2 + 1u;
  TFR(17) TFR(29) TFR(16) TFR(24)
  x0 += ks2; x1 += k0 + 2u;
  TFR(13) TFR(15) TFR(26) TFR(6)
  x0 += k0;  x1 += k1 + 3u;
  TFR(17) TFR(29) TFR(16) TFR(24)
  x0 += k1;  x1 += ks2 + 4u;
  TFR(13) TFR(15) TFR(26) TFR(6)
  x0 += ks2; x1 += k0 + 5u;
#undef TFR
  o0 = x0; o1 = x1;
}

__device__ inline float sigf(float x) { return 1.f / (1.f + __expf(-x)); }
__device__ inline float tanh_fast(float x) {
  float ax = fabsf(x);
  float t = __expf(-2.f * ax);
  float r = (1.f - t) / (1.f + t);
  return copysignf(r, x);
}
__device__ inline unsigned short f2bf(float f) {
  unsigned u = __float_as_uint(f);
  unsigned r = (u + 0x7FFFu + ((u >> 16) & 1u)) >> 16;
  return (unsigned short)r;
}
__device__ inline float bf2f(unsigned short u) {
  return __uint_as_float((unsigned)u << 16);
}

// coherent (agent-scope, L2-bypassing) state access — cross-XCD visible without L2 inv
__device__ inline unsigned long long ld_coh64(const void* ptr) {
  return __hip_atomic_load((unsigned long long*)ptr, __ATOMIC_RELAXED, __HIP_MEMORY_SCOPE_AGENT);
}
__device__ inline bf16x8 ld_coh16v(const unsigned short* ptr) {
  union { unsigned long long q[2]; bf16x8 v; } u;
  u.q[0] = __hip_atomic_load((unsigned long long*)ptr, __ATOMIC_RELAXED, __HIP_MEMORY_SCOPE_AGENT);
  u.q[1] = __hip_atomic_load(((unsigned long long*)ptr) + 1, __ATOMIC_RELAXED, __HIP_MEMORY_SCOPE_AGENT);
  return u.v;
}
__device__ inline void st_coh32(unsigned* ptr, unsigned v) {
  __hip_atomic_store(ptr, v, __ATOMIC_RELAXED, __HIP_MEMORY_SCOPE_AGENT);
}

#define LD4(p) (*(const float4*)(p))

// ---------------- mask generation (bit-packed) ----------------
__global__ void maskgen_kernel(Params p, unsigned k1a, unsigned k1b, unsigned k2a, unsigned k2b,
                               unsigned k3a, unsigned k3b, unsigned k4a, unsigned k4b) {
  int t = blockIdx.x * 256 + threadIdx.x;
  unsigned ka, kb; unsigned* dst; float pp;
  if (t < 512000)       { ka = k3a; kb = k3b; dst = p.mma; pp = 0.9f; }
  else if (t < 1024000) { t -= 512000;  ka = k4a; kb = k4b; dst = p.mmd; pp = 0.9f; }
  else if (t < 1152256) { t -= 1024000; ka = k1a; kb = k1b; dst = p.mm1; pp = 0.5f; }
  else if (t < 1280512) { t -= 1152256; ka = k2a; kb = k2b; dst = p.mm2; pp = 0.5f; }
  else return;
  unsigned word = 0u;
  for (int i = 0; i < 32; ++i) {
    unsigned o0, o1;
    tf_block(ka, kb, 0u, (unsigned)t * 32u + (unsigned)i, o0, o1);
#if TF_BITS_XOR
    unsigned bits = o0 ^ o1;
#else
    unsigned bits = o0;
#endif
    unsigned fb = (bits >> 9) | 0x3f800000u;
    float u = __uint_as_float(fb) - 1.0f;
    if (u < pp) word |= (1u << i);
  }
  dst[t] = word;
}

// ---------------- misc static prep ----------------
__global__ void prep_misc(Params p) {
  int i = blockIdx.x * 256 + threadIdx.x;
  if (i < 20480) { int k = i >> 8, u = i & 255; p.w1t[i] = p.pw1[u * 80 + k]; return; }
  i -= 20480;
  if (i < 65536) { int k = i >> 8, u = i & 255; p.w2t[i] = p.pw2[u * 256 + k]; return; }
  i -= 65536;
  if (i < 65536) { int k = i >> 7, a = i & 127; p.mwt[i] = p.mw[a * 512 + k]; return; }
  i -= 65536;
  if (i < 131072) { p.qw_bf[i] = f2bf(p.qw[i]); return; }
  i -= 131072;
  if (i < 4096) { int f = i >> 7, a = i & 127; p.ldwt[i] = p.ldw[a * 32 + f]; return; }
  i -= 4096;
  if (i < 4096) { int col = (i & 3) * 1024 + (i >> 2); p.ba[i] = p.abih[col] + p.abhh[col]; return; }
  i -= 4096;
  if (i < 4096) { int col = (i & 3) * 1024 + (i >> 2); p.bd[i] = p.dbih[col] + p.dbhh[col]; return; }
  i -= 4096;
  if (i < 4194304) { p.mem_bf[i] = f2bf(p.memory[i]); return; }
}

// ---------------- weight packing into MFMA B-fragment order ----------------
__global__ void pack_att(Params p) {
  int idx = blockIdx.x * 256 + threadIdx.x;
  if (idx >= 256 * 56 * 64) return;
  int l = idx & 63;
  int c = (idx >> 6) % 56;
  int T = idx / (56 * 64);
  int n = T * 16 + (l & 15);
  int col = (n & 3) * 1024 + (n >> 2);
  int kb = c * 32 + 8 * (l >> 4);
  bf16x8 v;
#pragma unroll
  for (int j = 0; j < 8; ++j) {
    int k = kb + j;
    float f = (k < 768) ? p.awih[(size_t)col * 768 + k] : p.awhh[(size_t)col * 1024 + k - 768];
    v[j] = (short)f2bf(f);
  }
  *(bf16x8*)(p.wpa + (size_t)idx * 8) = v;
}
__global__ void pack_dec(Params p) {
  int idx = blockIdx.x * 256 + threadIdx.x;
  if (idx >= 256 * 80 * 64) return;
  int l = idx & 63;
  int c = (idx >> 6) % 80;
  int T = idx / (80 * 64);
  int n = T * 16 + (l & 15);
  int col = (n & 3) * 1024 + (n >> 2);
  int kb = c * 32 + 8 * (l >> 4);
  bf16x8 v;
#pragma unroll
  for (int j = 0; j < 8; ++j) {
    int k = kb + j;
    float f = (k < 1536) ? p.dwih[(size_t)col * 1536 + k] : p.dwhh[(size_t)col * 1024 + k - 1536];
    v[j] = (short)f2bf(f);
  }
  *(bf16x8*)(p.wpd + (size_t)idx * 8) = v;
}

// ---------------- prenet ----------------
__global__ void prenet1_kernel(Params p) {
  __shared__ float din[8][80];
  int wg = blockIdx.x, tid = threadIdx.x;
  int r0 = wg * 8;
  for (int idx = tid; idx < 8 * 80; idx += 256) {
    int j = idx / 80, kk = idx % 80;
    int r = r0 + j; int t = r >> 5, b = r & 31;
    din[j][kk] = (t == 0) ? 0.f : p.dec_in[(size_t)b * 40000 + (size_t)kk * 500 + (t - 1)];
  }
  __syncthreads();
  float acc[8] = {0,0,0,0,0,0,0,0};
  for (int k = 0; k < 80; ++k) {
    float wv = p.w1t[k * 256 + tid];
#pragma unroll
    for (int j = 0; j < 8; ++j) acc[j] += din[j][k] * wv;
  }
  for (int j = 0; j < 8; ++j) {
    int r = r0 + j;
    unsigned e = (unsigned)r * 256u + tid;
    float mv = ((p.mm1[e >> 5] >> (e & 31)) & 1u) ? 2.0f : 0.0f;
    p.x1[(size_t)r * 256 + tid] = fmaxf(acc[j], 0.f) * mv;
  }
}
__global__ void prenet2_kernel(Params p) {
  __shared__ float rows[8][256];
  int wg = blockIdx.x, tid = threadIdx.x;
  int r0 = wg * 8;
  for (int idx = tid; idx < 8 * 256; idx += 256) {
    int j = idx >> 8, kk = idx & 255;
    rows[j][kk] = p.x1[(size_t)(r0 + j) * 256 + kk];
  }
  __syncthreads();
  float acc[8] = {0,0,0,0,0,0,0,0};
  for (int k = 0; k < 256; ++k) {
    float wv = p.w2t[k * 256 + tid];
#pragma unroll
    for (int j = 0; j < 8; ++j) acc[j] += rows[j][k] * wv;
  }
  for (int j = 0; j < 8; ++j) {
    int r = r0 + j;
    unsigned e = (unsigned)r * 256u + tid;
    float mv = ((p.mm2[e >> 5] >> (e & 31)) & 1u) ? 2.0f : 0.0f;
    p.pre_bf[(size_t)r * 256 + tid] = f2bf(fmaxf(acc[j], 0.f) * mv);
  }
}

// ---------------- processed_memory -> bf16 ----------------
__global__ void pm_kernel(Params p) {
  __shared__ float mrows[16][512];
  int wg = blockIdx.x;
  int b = wg >> 4, tc = wg & 15;
  int tid = threadIdx.x;
  int t0 = tc * 16;
  for (int idx = tid; idx < 16 * 512; idx += 128) {
    int i = idx >> 9, k = idx & 511;
    mrows[i][k] = p.memory[((size_t)b * 256 + t0 + i) * 512 + k];
  }
  __syncthreads();
  float acc[16];
#pragma unroll
  for (int i = 0; i < 16; ++i) acc[i] = 0.f;
  for (int k = 0; k < 512; ++k) {
    float wv = p.mwt[k * 128 + tid];
#pragma unroll
    for (int i = 0; i < 16; ++i) acc[i] += mrows[i][k] * wv;
  }
  for (int i = 0; i < 16; ++i)
    p.pm_bf[((size_t)b * 256 + t0 + i) * 128 + tid] = f2bf(acc[i]);
}

// ---------------- GEMM: two 16-col tiles/WG; weights cached, state coherent ----------------
template<int NC, int CPW, bool ATT>
__device__ __forceinline__ void gemm_tile2(const Params& p, int Tb, int lane, int v, int s,
                                           const unsigned short* ctxb_prev,
                                           const unsigned short* ahb_prev,
                                           const unsigned short* dhb_prev2,
                                           float* pl) {
  const unsigned short* wp = ATT ? p.wpa : p.wpd;
  const int arow = lane & 15;
  const int kgrp = (lane >> 4) * 8;
  bf16x8 bfa[CPW], bfb[CPW];
#pragma unroll
  for (int i = 0; i < CPW; ++i) {
    const unsigned short* bp = wp + ((size_t)(Tb * NC + v * CPW + i) * 64 + lane) * 8;
    bfa[i] = *(const bf16x8*)bp;
    bfb[i] = *(const bf16x8*)(bp + (size_t)NC * 64 * 8);
  }
  f32x4 acc00 = {0,0,0,0}, acc01 = {0,0,0,0}, acc10 = {0,0,0,0}, acc11 = {0,0,0,0};
#pragma unroll
  for (int i = 0; i < CPW; ++i) {
    const int c = v * CPW + i;
    const unsigned short* ab; int stride, k0; bool coh;
    if (ATT) {
      if (c < 8)       { ab = p.pre_bf + (size_t)s * 32 * 256; stride = 256;  k0 = c * 32;        coh = false; }
      else if (c < 24) { ab = ctxb_prev;                        stride = 512;  k0 = c * 32 - 256;  coh = true; }
      else             { ab = ahb_prev;                         stride = 1024; k0 = c * 32 - 768;  coh = true; }
    } else {
      if (c < 32)      { ab = ahb_prev;                         stride = 1024; k0 = c * 32;        coh = true; }
      else if (c < 48) { ab = ctxb_prev;                        stride = 512;  k0 = c * 32 - 1024; coh = true; }
      else             { ab = dhb_prev2;                        stride = 1024; k0 = c * 32 - 1536; coh = true; }
    }
    const unsigned short* ap = ab + (size_t)arow * stride + k0 + kgrp;
    bf16x8 a0 = coh ? ld_coh16v(ap) : *(const bf16x8*)ap;
    bf16x8 a1 = coh ? ld_coh16v(ap + 16 * stride) : *(const bf16x8*)(ap + 16 * stride);
    acc00 = __builtin_amdgcn_mfma_f32_16x16x32_bf16(a0, bfa[i], acc00, 0, 0, 0);
    acc01 = __builtin_amdgcn_mfma_f32_16x16x32_bf16(a1, bfa[i], acc01, 0, 0, 0);
    acc10 = __builtin_amdgcn_mfma_f32_16x16x32_bf16(a0, bfb[i], acc10, 0, 0, 0);
    acc11 = __builtin_amdgcn_mfma_f32_16x16x32_bf16(a1, bfb[i], acc11, 0, 0, 0);
  }
  const int po = (lane & 15) * 17 + (lane >> 4) * 4;
#pragma unroll
  for (int j = 0; j < 4; ++j) {
    pl[v * 1088 +   0 + po + j] = acc00[j];
    pl[v * 1088 + 272 + po + j] = acc01[j];
    pl[v * 1088 + 544 + po + j] = acc10[j];
    pl[v * 1088 + 816 + po + j] = acc11[j];
  }
}

// ---------------- persistent scan kernel (custom non-invalidating barrier) ----------------
__global__ void __launch_bounds__(512) scan_kernel(Params p) {
  const int wg = blockIdx.x;
  const int tid = threadIdx.x;
  const int lane = tid & 63;
  const int v = tid >> 6;

  __shared__ float pl[8 * 1088];    // phase-X partials; phase-B alias: locT_bf + ldwt_l
  __shared__ float gates[32 * 33];
  __shared__ float cst[256];
  __shared__ float aw_l[292], awc_l[292];  // padded aw/awcum, persistent (attention WGs)
  __shared__ float sm[1536];
  __shared__ unsigned short ahst[1536];
  __shared__ unsigned short cxst[512];
  __shared__ unsigned short hst[256];

  if (tid < 256) cst[tid] = 0.f;
  if (tid < 292) { aw_l[tid] = 0.f; awc_l[tid] = 0.f; }

  unsigned bargen = 0;
  auto gbar = [&]() {
    ++bargen;
    __syncthreads();
    if (tid == 0) {
      unsigned old = __hip_atomic_fetch_add(&p.barc[bargen & 1], 1u, __ATOMIC_RELEASE, __HIP_MEMORY_SCOPE_AGENT);
      if (old == 255u) {
        __hip_atomic_store(&p.barc[bargen & 1], 0u, __ATOMIC_RELAXED, __HIP_MEMORY_SCOPE_AGENT);
        __hip_atomic_store(p.barg, bargen, __ATOMIC_RELEASE, __HIP_MEMORY_SCOPE_AGENT);
      } else {
        while (__hip_atomic_load(p.barg, __ATOMIC_RELAXED, __HIP_MEMORY_SCOPE_AGENT) < bargen)
          __builtin_amdgcn_s_sleep(2);
      }
    }
    __syncthreads();
  };

  const bool is_att = wg < 128;
  const int wg2 = wg - 128;

  for (int s = 0; s <= 500; ++s) {
    const int sb = s & 1;
    const unsigned short* ahb_prev  = sb ? p.ahb0 : p.ahb1;
    unsigned short*       ahb_cur   = sb ? p.ahb1 : p.ahb0;
    const unsigned short* dhb_prev2 = sb ? p.dhb1 : p.dhb0;
    unsigned short*       dhb_out   = sb ? p.dhb0 : p.dhb1;
    const unsigned short* ctxb_prev = sb ? p.ctxb0 : p.ctxb1;
    unsigned short*       ctxb_cur  = sb ? p.ctxb1 : p.ctxb0;

    const bool gemm_on = is_att ? (s < 500) : (s >= 1);

    // ================= Phase X: LSTM gate GEMMs =================
    if (gemm_on) {
      if (is_att) gemm_tile2<56, 7, true >(p, wg  * 2, lane, v, s, ctxb_prev, ahb_prev, dhb_prev2, pl);
      else        gemm_tile2<80, 10, false>(p, wg2 * 2, lane, v, s, ctxb_prev, ahb_prev, dhb_prev2, pl);
    }
    __syncthreads();
    if (gemm_on) {
      const float* bias = is_att ? p.ba : p.bd;
      const int nb32 = (is_att ? wg : wg2) * 32;
#pragma unroll
      for (int rep = 0; rep < 2; ++rep) {
        int o = rep * 512 + tid;
        int tile = o >> 9, half = (o >> 8) & 1, n = (o >> 4) & 15, brow = o & 15;
        int o2 = (tile * 2 + half) * 272 + n * 17 + brow;
        float acc = 0.f;
#pragma unroll
        for (int w = 0; w < 8; ++w) acc += pl[w * 1088 + o2];
        int n_local = tile * 16 + n;
        gates[n_local * 33 + half * 16 + brow] = acc + bias[nb32 + n_local];
      }
    }
    __syncthreads();
    if (gemm_on && tid < 256) {
      int u_local = tid >> 5, b = tid & 31;
      float gi = gates[(u_local * 4 + 0) * 33 + b];
      float gf = gates[(u_local * 4 + 1) * 33 + b];
      float gg = gates[(u_local * 4 + 2) * 33 + b];
      float go = gates[(u_local * 4 + 3) * 33 + b];
      float I = sigf(gi), F = sigf(gf), G = tanh_fast(gg), O = sigf(go);
      float c2 = F * cst[tid] + I * G;
      float h = O * tanh_fast(c2);
      cst[tid] = c2;
      int u = (is_att ? wg : wg2) * 8 + u_local;
      float mv;
      if (is_att) {
        unsigned e = ((unsigned)s * 32 + b) * 1024u + u;
        mv = ((p.mma[e >> 5] >> (e & 31)) & 1u) ? (1.f / 0.9f) : 0.f;
      } else {
        unsigned e = ((unsigned)(s - 1) * 32 + b) * 1024u + u;
        mv = ((p.mmd[e >> 5] >> (e & 31)) & 1u) ? (1.f / 0.9f) : 0.f;
      }
      hst[tid] = f2bf(h * mv);
    }
    __syncthreads();
    if (gemm_on && tid < 128) {
      int j = tid >> 5, bb = tid & 31;
      unsigned lo = hst[j * 64 + bb], hi = hst[j * 64 + 32 + bb];
      unsigned val = lo | (hi << 16);
      unsigned short* basep = is_att ? ahb_cur : dhb_out;
      int T8 = (is_att ? wg : wg2) * 8;
      st_coh32((unsigned*)(basep + (size_t)bb * 1024 + T8 + 2 * j), val);
    }

    gbar();

    // ================= Phase B =================
    if (wg < 32) {
      if (s < 500) {
        const int b = wg;
        unsigned short* locT_bf = (unsigned short*)pl;          // 32 x 260 bf16
        float* ldwt_l = (float*)((char*)(void*)pl + 16640);     // 32 x 128 fp32
        // (1) fill ldwt_l; stage ahb_cur[b]; conv -> locT_bf
        {
          const float4* srcw = (const float4*)p.ldwt;
          float4* dstw = (float4*)ldwt_l;
          dstw[tid] = srcw[tid];
          dstw[tid + 512] = srcw[tid + 512];
        }
        if (tid < 256) {
          unsigned long long q = ld_coh64((const unsigned long long*)(ahb_cur + (size_t)b * 1024) + tid);
          *(unsigned long long*)&ahst[tid * 4] = q;
        }
#pragma unroll
        for (int rep = 0; rep < 4; ++rep) {
          int qd = rep * 512 + tid;
          int f = qd >> 6, tq = (qd & 63) * 4;
          const float* wf = p.lcw + f * 62;
          float w[36]; float acc[4] = {0, 0, 0, 0};
#pragma unroll
          for (int j2 = 0; j2 < 9; ++j2) {
            float4 x = *(const float4*)&aw_l[tq + j2 * 4];
            w[j2*4] = x.x; w[j2*4+1] = x.y; w[j2*4+2] = x.z; w[j2*4+3] = x.w;
          }
#pragma unroll
          for (int k = 0; k < 31; ++k) {
            float cc = wf[k];
            acc[0] += w[k+1]*cc; acc[1] += w[k+2]*cc; acc[2] += w[k+3]*cc; acc[3] += w[k+4]*cc;
          }
#pragma unroll
          for (int j2 = 0; j2 < 9; ++j2) {
            float4 x = *(const float4*)&awc_l[tq + j2 * 4];
            w[j2*4] = x.x; w[j2*4+1] = x.y; w[j2*4+2] = x.z; w[j2*4+3] = x.w;
          }
#pragma unroll
          for (int k = 0; k < 31; ++k) {
            float cc = wf[31 + k];
            acc[0] += w[k+1]*cc; acc[1] += w[k+2]*cc; acc[2] += w[k+3]*cc; acc[3] += w[k+4]*cc;
          }
#pragma unroll
          for (int j2 = 0; j2 < 4; ++j2) locT_bf[f * 260 + tq + j2] = f2bf(acc[j2]);
        }
        __syncthreads();
        // (2) pq partials from staged ah (bf16) x qw_bf
        {
          int a = tid & 127, kq = tid >> 7;
          const unsigned short* qp = p.qw_bf + (size_t)a * 1024 + kq * 256;
          float acc = 0.f;
#pragma unroll 4
          for (int j = 0; j < 256; j += 8) {
            bf16x8 qv = *(const bf16x8*)(qp + j);
            bf16x8 av = *(const bf16x8*)&ahst[kq * 256 + j];
#pragma unroll
            for (int j2 = 0; j2 < 8; ++j2)
              acc += bf2f((unsigned short)av[j2]) * bf2f((unsigned short)qv[j2]);
          }
          sm[256 + kq * 128 + a] = acc;
          if (tid < 128) sm[128 + tid] = p.vw[tid];
        }
        __syncthreads();
        if (tid < 128) sm[tid] = sm[256 + tid] + sm[384 + tid] + sm[512 + tid] + sm[640 + tid];
        __syncthreads();
        // (3) energies with fused location-dense
        {
          int t = tid & 255, h2 = tid >> 8;
          float lt[32];
#pragma unroll
          for (int f = 0; f < 32; ++f) lt[f] = bf2f(locT_bf[f * 260 + t]);
          const unsigned short* pmp = p.pm_bf + ((size_t)b * 256 + t) * 128;
          float e = 0.f;
#pragma unroll 2
          for (int ac = 0; ac < 16; ++ac) {
            int a0 = h2 * 64 + ac * 4;
            float4 l2 = {0, 0, 0, 0};
#pragma unroll
            for (int f = 0; f < 32; ++f) {
              float4 wv = *(const float4*)&ldwt_l[f * 128 + a0];
              l2.x += lt[f]*wv.x; l2.y += lt[f]*wv.y; l2.z += lt[f]*wv.z; l2.w += lt[f]*wv.w;
            }
            ushort4_t pv = *(const ushort4_t*)(pmp + a0);
            e += tanh_fast(sm[a0+0] + l2.x + bf2f(pv.x)) * sm[128+a0+0];
            e += tanh_fast(sm[a0+1] + l2.y + bf2f(pv.y)) * sm[128+a0+1];
            e += tanh_fast(sm[a0+2] + l2.z + bf2f(pv.z)) * sm[128+a0+2];
            e += tanh_fast(sm[a0+3] + l2.w + bf2f(pv.w)) * sm[128+a0+3];
          }
          sm[256 + h2 * 256 + t] = e;
        }
        __syncthreads();
        if (tid < 256) {
          float en = sm[256 + tid] + sm[512 + tid];
          float w = (tid < p.mlen[b]) ? __expf(en) : 0.f;
          sm[768 + tid] = w;
        }
        __syncthreads();
        if (tid < 32) {
          float sub = 0.f;
#pragma unroll
          for (int i = 0; i < 8; ++i) sub += sm[768 + tid * 8 + i];
          sm[256 + tid] = sub;
        }
        __syncthreads();
        if (tid == 0) {
          float S = 0.f;
#pragma unroll
          for (int i = 0; i < 32; ++i) S += sm[256 + i];
          sm[1281] = 1.f / S;
        }
        __syncthreads();
        if (tid < 256) {
          float awv = sm[768 + tid] * sm[1281];
          aw_l[16 + tid] = awv;
          awc_l[16 + tid] += awv;
          p.out[(size_t)AOFF + (size_t)b * 128000 + (size_t)s * 256 + tid] = awv;
          sm[1024 + tid] = awv;
        }
        __syncthreads();
        {
          const unsigned short* mb = p.mem_bf + (size_t)b * 131072 + tid;
          float acc = 0.f;
#pragma unroll 8
          for (int t2 = 0; t2 < 256; ++t2) acc += sm[1024 + t2] * bf2f(mb[(size_t)t2 * 512]);
          cxst[tid] = f2bf(acc);
        }
        __syncthreads();
        if (tid < 256) {
          unsigned val = (unsigned)cxst[2 * tid] | ((unsigned)cxst[2 * tid + 1] << 16);
          st_coh32((unsigned*)(ctxb_cur + (size_t)b * 512 + 2 * tid), val);
        }
      }
    } else {
      if (s >= 1) {
        int idx = wg - 32;
        int b = idx / 7, c7 = idx % 7;
        int m0 = c7 * 12, mc = (c7 == 6) ? 8 : 12;
        // stage dh_{s-1}[b] (1024 bf16 = 256 qwords) + ctx_{s-1}[b] (512 bf16 = 128 qwords)
        if (tid < 384) {
          unsigned long long q;
          if (tid < 256) q = ld_coh64((const unsigned long long*)(dhb_out + (size_t)b * 1024) + tid);
          else           q = ld_coh64((const unsigned long long*)(ctxb_prev + (size_t)b * 512) + (tid - 256));
          *(unsigned long long*)&ahst[tid * 4] = q;
        }
        __syncthreads();
        int mi = tid >> 5, kg = tid & 31;
        if (mi < mc) {
          int m = m0 + mi;
          const float* pw = p.pjw + (size_t)m * 1536 + kg * 48;
          float acc = 0.f;
#pragma unroll 4
          for (int j = 0; j < 48; ++j) acc += bf2f(ahst[kg * 48 + j]) * pw[j];
          sm[mi * 32 + kg] = acc;
        }
        if (c7 == 6 && tid >= 384) {
          int kg2 = tid - 384;
          const float* gwp = p.gw + kg2 * 12;
          float acc = 0.f;
#pragma unroll
          for (int j = 0; j < 12; ++j) acc += bf2f(ahst[kg2 * 12 + j]) * gwp[j];
          sm[512 + kg2] = acc;
        }
        __syncthreads();
        if (tid < mc) {
          float r = p.pjb[m0 + tid];
#pragma unroll
          for (int j = 0; j < 32; ++j) r += sm[tid * 32 + j];
          p.out[(size_t)b * 40000 + (size_t)(m0 + tid) * 500 + (s - 1)] = r;
        }
        if (c7 == 6 && tid == 384) {
          float r = p.gb[0];
#pragma unroll
          for (int j = 0; j < 128; ++j) r += sm[512 + j];
          p.out[(size_t)GOFF + (size_t)b * 500 + (s - 1)] = r;
        }
      }
    }

    gbar();
  }
}

// ---------------- host ----------------
extern "C" void kernel_launch(void* const* d_in, const int* in_sizes, int n_in,
                              void* d_out, int out_size, void* d_ws, size_t ws_size,
                              hipStream_t stream) {
  Params p;
  p.memory = (const float*)d_in[0];
  p.dec_in = (const float*)d_in[1];
  p.mlen   = (const int*)d_in[2];
  p.pw1  = (const float*)d_in[3];
  p.pw2  = (const float*)d_in[4];
  p.awih = (const float*)d_in[5];
  p.awhh = (const float*)d_in[6];
  p.abih = (const float*)d_in[7];
  p.abhh = (const float*)d_in[8];
  p.qw   = (const float*)d_in[9];
  p.mw   = (const float*)d_in[10];
  p.vw   = (const float*)d_in[11];
  p.lcw  = (const float*)d_in[12];
  p.ldw  = (const float*)d_in[13];
  p.dwih = (const float*)d_in[14];
  p.dwhh = (const float*)d_in[15];
  p.dbih = (const float*)d_in[16];
  p.dbhh = (const float*)d_in[17];
  p.pjw  = (const float*)d_in[18];
  p.pjb  = (const float*)d_in[19];
  p.gw   = (const float*)d_in[20];
  p.gb   = (const float*)d_in[21];
  p.out  = (float*)d_out;

  char* cur = (char*)d_ws;
  auto allocf = [&](size_t n) { float* r = (float*)cur; cur += n * sizeof(float); return r; };
  auto allocs = [&](size_t n) { unsigned short* r = (unsigned short*)cur; cur += n * sizeof(unsigned short); return r; };
  // mutable state (memset each launch)
  p.ahb0 = allocs(32 * 1024); p.ahb1 = allocs(32 * 1024);
  p.dhb0 = allocs(32 * 1024); p.dhb1 = allocs(32 * 1024);
  p.ctxb0 = allocs(32 * 512); p.ctxb1 = allocs(32 * 512);
  p.barc = (unsigned*)cur; cur += 2 * sizeof(unsigned);
  p.barg = (unsigned*)cur; cur += sizeof(unsigned);
  cur += 60;  // pad to 64B
  size_t state_bytes = (size_t)(cur - (char*)d_ws);
  // static
  p.x1   = allocf((size_t)500 * 32 * 256);
  p.w1t  = allocf(80 * 256);
  p.w2t  = allocf(256 * 256);
  p.mwt  = allocf(512 * 128);
  p.ldwt = allocf(32 * 128);
  p.ba   = allocf(4096);
  p.bd   = allocf(4096);
  p.pre_bf  = allocs((size_t)500 * 32 * 256);
  p.pm_bf   = allocs((size_t)32 * 256 * 128);
  p.mem_bf  = allocs((size_t)32 * 256 * 512);
  p.qw_bf   = allocs(128 * 1024);
  p.wpa     = allocs((size_t)256 * 56 * 64 * 8);
  p.wpd     = allocs((size_t)256 * 80 * 64 * 8);
  p.mma = (unsigned*)cur; cur += 512000u * 4;
  p.mmd = (unsigned*)cur; cur += 512000u * 4;
  p.mm1 = (unsigned*)cur; cur += 128256u * 4;
  p.mm2 = (unsigned*)cur; cur += 128256u * 4;

  (void)hipMemsetAsync(d_ws, 0, state_bytes, stream);

  unsigned k[8];
  {
    unsigned o0, o1;
    tf_block(0u, 1u, 0u, 0u, o0, o1); k[0] = o0; k[1] = o1;
    tf_block(0u, 1u, 0u, 1u, o0, o1); k[2] = o0; k[3] = o1;
    tf_block(0u, 1u, 0u, 2u, o0, o1); k[4] = o0; k[5] = o1;
    tf_block(0u, 1u, 0u, 3u, o0, o1); k[6] = o0; k[7] = o1;
  }

  maskgen_kernel<<<(1280512 + 255) / 256, 256, 0, stream>>>(p, k[0], k[1], k[2], k[3], k[4], k[5], k[6], k[7]);
  prep_misc<<<(4489216 + 255) / 256, 256, 0, stream>>>(p);
  pack_att<<<(917504 + 255) / 256, 256, 0, stream>>>(p);
  pack_dec<<<(1310720 + 255) / 256, 256, 0, stream>>>(p);
  prenet1_kernel<<<2000, 256, 0, stream>>>(p);
  prenet2_kernel<<<2000, 256, 0, stream>>>(p);
  pm_kernel<<<512, 128, 0, stream>>>(p);

  void* args[] = { (void*)&p };
  (void)hipLaunchCooperativeKernel((const void*)scan_kernel, dim3(256), dim3(512), args, 0, stream);
}